// Round 1
// baseline (790.682 us; speedup 1.0000x reference)
//
#include <hip/hip_runtime.h>

#define N_NODES 50000
#define N_EDGES 800000
#define D 128
#define LABEL_DIM 32
#define REL_DIM 32
#define REL_BUCKETS 1024
#define LN_EPS 1e-5f

// ---------------- CSR build ----------------

__global__ __launch_bounds__(256) void count_deg_kernel(const int* __restrict__ dst,
                                                        int* __restrict__ deg) {
    int e = blockIdx.x * 256 + threadIdx.x;
    if (e < N_EDGES) atomicAdd(&deg[dst[e]], 1);
}

// single-block scan over 50000 degrees -> exclusive offsets (+ cursor copy)
__global__ __launch_bounds__(1024) void scan_kernel(const int* __restrict__ deg,
                                                    int* __restrict__ offsets,
                                                    int* __restrict__ cursor) {
    __shared__ int buf[1024];
    __shared__ int s_carry;
    if (threadIdx.x == 0) s_carry = 0;
    __syncthreads();
    for (int base = 0; base < N_NODES; base += 1024) {
        int i = base + (int)threadIdx.x;
        int v = (i < N_NODES) ? deg[i] : 0;
        buf[threadIdx.x] = v;
        __syncthreads();
        for (int off = 1; off < 1024; off <<= 1) {
            int t = (threadIdx.x >= (unsigned)off) ? buf[threadIdx.x - off] : 0;
            __syncthreads();
            buf[threadIdx.x] += t;
            __syncthreads();
        }
        int incl = buf[threadIdx.x];
        int carry = s_carry;
        if (i < N_NODES) {
            int o = carry + incl - v;
            offsets[i] = o;
            cursor[i] = o;
        }
        __syncthreads();
        if (threadIdx.x == 1023) s_carry = carry + buf[1023];
        __syncthreads();
    }
    if (threadIdx.x == 0) offsets[N_NODES] = s_carry;
}

__global__ __launch_bounds__(256) void fill_csr_kernel(const int* __restrict__ src,
                                                       const int* __restrict__ dst,
                                                       const int* __restrict__ rel,
                                                       int* __restrict__ cursor,
                                                       int* __restrict__ csr_src,
                                                       int* __restrict__ csr_rel) {
    int e = blockIdx.x * 256 + threadIdx.x;
    if (e < N_EDGES) {
        int d = dst[e];
        int pos = atomicAdd(&cursor[d], 1);
        csr_src[pos] = src[e];
        csr_rel[pos] = rel[e];
    }
}

// ---------------- GEMM: Y[N,128] = X[N,128] @ W[128,128] (+bias) ----------------
// 256 threads, 64 rows/block. Thread tile: 4 rows x 8 cols (cols tx*4 and 64+tx*4
// to keep LDS W reads 2-way-bank-aliased only, which is free).
__global__ __launch_bounds__(256) void gemm128_kernel(const float* __restrict__ X,
                                                      const float* __restrict__ W,
                                                      const float* __restrict__ bias,
                                                      float* __restrict__ Y) {
    __shared__ float sw[128 * 128];  // 64 KiB
    {
        const float4* w4 = (const float4*)W;
        float4* s4 = (float4*)sw;
        for (int i = threadIdx.x; i < 128 * 128 / 4; i += 256) s4[i] = w4[i];
    }
    __syncthreads();

    const int tx = threadIdx.x & 15;   // col group
    const int ty = threadIdx.x >> 4;   // row group (0..15)
    const int r0 = blockIdx.x * 64 + ty * 4;
    const int cA = tx * 4, cB = 64 + tx * 4;

    float acc[4][8];
#pragma unroll
    for (int i = 0; i < 4; i++)
#pragma unroll
        for (int j = 0; j < 4; j++) {
            float bA = bias ? bias[cA + j] : 0.f;
            float bB = bias ? bias[cB + j] : 0.f;
            acc[i][j] = bA;
            acc[i][4 + j] = bB;
        }

    for (int k = 0; k < 128; k += 4) {
        float4 xv[4];
#pragma unroll
        for (int i = 0; i < 4; i++) {
            int r = r0 + i;
            xv[i] = (r < N_NODES) ? *(const float4*)(X + (size_t)r * 128 + k)
                                  : make_float4(0.f, 0.f, 0.f, 0.f);
        }
#pragma unroll
        for (int kk = 0; kk < 4; kk++) {
            float4 w0 = *(const float4*)(sw + (k + kk) * 128 + cA);
            float4 w1 = *(const float4*)(sw + (k + kk) * 128 + cB);
#pragma unroll
            for (int i = 0; i < 4; i++) {
                float xs = ((const float*)&xv[i])[kk];
                acc[i][0] = fmaf(xs, w0.x, acc[i][0]);
                acc[i][1] = fmaf(xs, w0.y, acc[i][1]);
                acc[i][2] = fmaf(xs, w0.z, acc[i][2]);
                acc[i][3] = fmaf(xs, w0.w, acc[i][3]);
                acc[i][4] = fmaf(xs, w1.x, acc[i][4]);
                acc[i][5] = fmaf(xs, w1.y, acc[i][5]);
                acc[i][6] = fmaf(xs, w1.z, acc[i][6]);
                acc[i][7] = fmaf(xs, w1.w, acc[i][7]);
            }
        }
    }
#pragma unroll
    for (int i = 0; i < 4; i++) {
        int r = r0 + i;
        if (r < N_NODES) {
            *(float4*)(Y + (size_t)r * 128 + cA) =
                make_float4(acc[i][0], acc[i][1], acc[i][2], acc[i][3]);
            *(float4*)(Y + (size_t)r * 128 + cB) =
                make_float4(acc[i][4], acc[i][5], acc[i][6], acc[i][7]);
        }
    }
}

// ---------------- input proj epilogue: h += label_emb[label] @ W[128:160], relu ----
__global__ __launch_bounds__(256) void add_label_relu_kernel(const int* __restrict__ label,
                                                             const float* __restrict__ label_emb,
                                                             const float* __restrict__ Wl,  // [32][128]
                                                             float* __restrict__ h) {
    __shared__ float sw[LABEL_DIM * 128];  // 16 KiB
    for (int i = threadIdx.x; i < LABEL_DIM * 128; i += 256) sw[i] = Wl[i];
    __syncthreads();
    int idx = blockIdx.x * 256 + threadIdx.x;  // N*128 total, exact multiple
    int r = idx >> 7, c = idx & 127;
    int lb = label[r];
    float a = h[idx];
    const float* le = label_emb + (size_t)lb * LABEL_DIM;
#pragma unroll
    for (int k = 0; k < LABEL_DIM; k++) a = fmaf(le[k], sw[k * 128 + c], a);
    h[idx] = fmaxf(a, 0.f);
}

// ---------------- relW[1024,128] = rel_emb[l] @ lin_rel_w[l] ----------------
__global__ __launch_bounds__(256) void relw_kernel(const float* __restrict__ rel_emb,  // [1024][32]
                                                   const float* __restrict__ Wr,       // [32][128]
                                                   float* __restrict__ relW) {
    __shared__ float sw[REL_DIM * 128];
    for (int i = threadIdx.x; i < REL_DIM * 128; i += 256) sw[i] = Wr[i];
    __syncthreads();
    int idx = blockIdx.x * 256 + threadIdx.x;  // 1024*128 total, exact
    int r = idx >> 7, c = idx & 127;
    const float* re = rel_emb + (size_t)r * REL_DIM;
    float a = 0.f;
#pragma unroll
    for (int k = 0; k < REL_DIM; k++) a = fmaf(re[k], sw[k * 128 + c], a);
    relW[idx] = a;
}

// ---------------- edge gather + mean + self + relu + layernorm ----------------
// one block per node, 128 threads = 128 feature dims
__global__ __launch_bounds__(128) void agg_ln_kernel(const float* __restrict__ hW,
                                                     const float* __restrict__ relW,
                                                     const float* __restrict__ hs,
                                                     const int* __restrict__ offsets,
                                                     const int* __restrict__ csr_src,
                                                     const int* __restrict__ csr_rel,
                                                     const float* __restrict__ g,
                                                     const float* __restrict__ b,
                                                     float* __restrict__ h) {
    int node = blockIdx.x;
    int c = threadIdx.x;
    int beg = offsets[node], end = offsets[node + 1];

    __shared__ int s_src[128];
    __shared__ int s_rel[128];
    float acc = 0.f;
    for (int base = beg; base < end; base += 128) {
        int m = min(128, end - base);
        if (c < m) {
            s_src[c] = csr_src[base + c];
            s_rel[c] = csr_rel[base + c];
        }
        __syncthreads();
        for (int i = 0; i < m; i++)
            acc += hW[(size_t)s_src[i] * 128 + c] + relW[(size_t)s_rel[i] * 128 + c];
        __syncthreads();
    }

    float inv = (end > beg) ? 1.f / (float)(end - beg) : 0.f;
    float v = hs[(size_t)node * 128 + c] + acc * inv;
    v = fmaxf(v, 0.f);

    __shared__ float red[128];
    red[c] = v;
    __syncthreads();
    for (int s = 64; s > 0; s >>= 1) {
        if (c < s) red[c] += red[c + s];
        __syncthreads();
    }
    float mu = red[0] * (1.f / 128.f);
    __syncthreads();
    float d = v - mu;
    red[c] = d * d;
    __syncthreads();
    for (int s = 64; s > 0; s >>= 1) {
        if (c < s) red[c] += red[c + s];
        __syncthreads();
    }
    float var = red[0] * (1.f / 128.f);
    float out = d * rsqrtf(var + LN_EPS) * g[c] + b[c];
    h[(size_t)node * 128 + c] = out;
}

// ---------------- launch ----------------

extern "C" void kernel_launch(void* const* d_in, const int* in_sizes, int n_in,
                              void* d_out, int out_size, void* d_ws, size_t ws_size,
                              hipStream_t stream) {
    const float* x          = (const float*)d_in[0];
    const int*   label      = (const int*)d_in[1];
    const int*   edge_index = (const int*)d_in[2];
    const int*   edge_rel   = (const int*)d_in[3];
    const float* label_emb  = (const float*)d_in[4];
    const float* in_proj_w  = (const float*)d_in[5];
    const float* in_proj_b  = (const float*)d_in[6];
    const float* rel_emb    = (const float*)d_in[7];
    const float* lin_neigh_w = (const float*)d_in[8];
    const float* lin_self_w  = (const float*)d_in[9];
    const float* lin_self_b  = (const float*)d_in[10];
    const float* lin_rel_w   = (const float*)d_in[11];
    const float* ln_g        = (const float*)d_in[12];
    const float* ln_b        = (const float*)d_in[13];
    float* h = (float*)d_out;

    char* p = (char*)d_ws;
    auto alloc = [&](size_t bytes) {
        char* r = p;
        p += (bytes + 255) & ~(size_t)255;
        return r;
    };
    int* deg      = (int*)alloc((size_t)N_NODES * 4);
    int* offsets  = (int*)alloc((size_t)(N_NODES + 1) * 4);
    int* cursor   = (int*)alloc((size_t)N_NODES * 4);
    int* csr_src  = (int*)alloc((size_t)N_EDGES * 4);
    int* csr_rel  = (int*)alloc((size_t)N_EDGES * 4);
    float* hW     = (float*)alloc((size_t)N_NODES * 128 * 4);
    float* hs     = (float*)alloc((size_t)N_NODES * 128 * 4);
    float* relW   = (float*)alloc((size_t)REL_BUCKETS * 128 * 4);

    const int* src = edge_index;
    const int* dst = edge_index + N_EDGES;

    // CSR build (edges constant across layers -> build once per call)
    hipMemsetAsync(deg, 0, (size_t)N_NODES * 4, stream);
    count_deg_kernel<<<(N_EDGES + 255) / 256, 256, 0, stream>>>(dst, deg);
    scan_kernel<<<1, 1024, 0, stream>>>(deg, offsets, cursor);
    fill_csr_kernel<<<(N_EDGES + 255) / 256, 256, 0, stream>>>(src, dst, edge_rel, cursor,
                                                               csr_src, csr_rel);

    // input projection: h = relu(x @ W[:128] + label_emb[label] @ W[128:] + b)
    gemm128_kernel<<<(N_NODES + 63) / 64, 256, 0, stream>>>(x, in_proj_w, in_proj_b, h);
    add_label_relu_kernel<<<(N_NODES * 128) / 256, 256, 0, stream>>>(
        label, label_emb, in_proj_w + 128 * 128, h);

    for (int l = 0; l < 2; l++) {
        relw_kernel<<<(REL_BUCKETS * 128) / 256, 256, 0, stream>>>(
            rel_emb + (size_t)l * REL_BUCKETS * REL_DIM, lin_rel_w + (size_t)l * REL_DIM * 128,
            relW);
        gemm128_kernel<<<(N_NODES + 63) / 64, 256, 0, stream>>>(
            h, lin_neigh_w + (size_t)l * 128 * 128, nullptr, hW);
        gemm128_kernel<<<(N_NODES + 63) / 64, 256, 0, stream>>>(
            h, lin_self_w + (size_t)l * 128 * 128, lin_self_b + (size_t)l * 128, hs);
        agg_ln_kernel<<<N_NODES, 128, 0, stream>>>(hW, relW, hs, offsets, csr_src, csr_rel,
                                                   ln_g + (size_t)l * 128, ln_b + (size_t)l * 128,
                                                   h);
    }
}

// Round 2
// 698.568 us; speedup vs baseline: 1.1319x; 1.1319x over previous
//
#include <hip/hip_runtime.h>
#include <hip/hip_bf16.h>

#define N_NODES 50000
#define N_EDGES 800000
#define D 128
#define LABEL_DIM 32
#define REL_DIM 32
#define REL_BUCKETS 1024
#define LN_EPS 1e-5f

#define SCAN_TILE 1024
#define N_SCAN_BLOCKS ((N_NODES + SCAN_TILE - 1) / SCAN_TILE)  // 49

__device__ inline unsigned short f2bf(float f) {
    __hip_bfloat16 h = __float2bfloat16(f);
    return *reinterpret_cast<unsigned short*>(&h);
}

// ---------------- CSR build ----------------

__global__ __launch_bounds__(256) void count_deg_kernel(const int* __restrict__ dst,
                                                        int* __restrict__ deg) {
    int e = blockIdx.x * 256 + threadIdx.x;
    if (e < N_EDGES) atomicAdd(&deg[dst[e]], 1);
}

// tile-local exclusive scan: offsets[i] = exclusive-within-block, blockSums[b] = block total
__global__ __launch_bounds__(SCAN_TILE) void scan_tiles_kernel(const int* __restrict__ deg,
                                                               int* __restrict__ offsets,
                                                               int* __restrict__ blockSums) {
    __shared__ int buf[SCAN_TILE];
    int i = blockIdx.x * SCAN_TILE + threadIdx.x;
    int v = (i < N_NODES) ? deg[i] : 0;
    buf[threadIdx.x] = v;
    __syncthreads();
    for (int off = 1; off < SCAN_TILE; off <<= 1) {
        int t = (threadIdx.x >= (unsigned)off) ? buf[threadIdx.x - off] : 0;
        __syncthreads();
        buf[threadIdx.x] += t;
        __syncthreads();
    }
    if (i < N_NODES) offsets[i] = buf[threadIdx.x] - v;
    if (threadIdx.x == SCAN_TILE - 1) blockSums[blockIdx.x] = buf[SCAN_TILE - 1];
}

// serial exclusive scan of the 49 block sums (trivial size)
__global__ void scan_sums_kernel(int* __restrict__ blockSums, int* __restrict__ offsets) {
    if (threadIdx.x == 0 && blockIdx.x == 0) {
        int run = 0;
        for (int i = 0; i < N_SCAN_BLOCKS; i++) {
            int v = blockSums[i];
            blockSums[i] = run;
            run += v;
        }
        offsets[N_NODES] = run;
    }
}

__global__ __launch_bounds__(SCAN_TILE) void scan_add_kernel(int* __restrict__ offsets,
                                                             const int* __restrict__ blockSums,
                                                             int* __restrict__ cursor) {
    int i = blockIdx.x * SCAN_TILE + threadIdx.x;
    if (i < N_NODES) {
        int o = offsets[i] + blockSums[blockIdx.x];
        offsets[i] = o;
        cursor[i] = o;
    }
}

__global__ __launch_bounds__(256) void fill_csr_kernel(const int* __restrict__ src,
                                                       const int* __restrict__ dst,
                                                       const int* __restrict__ rel,
                                                       int* __restrict__ cursor,
                                                       int* __restrict__ csr_src,
                                                       int* __restrict__ csr_rel) {
    int e = blockIdx.x * 256 + threadIdx.x;
    if (e < N_EDGES) {
        int d = dst[e];
        int pos = atomicAdd(&cursor[d], 1);
        csr_src[pos] = src[e];
        csr_rel[pos] = rel[e];
    }
}

// ---------------- GEMM: Y[N,128] = X[N,128] @ W[128,128] (+bias) ----------------
// 256 threads, 64 rows/block, 4x8 register tile. BF16OUT stores bf16 rows (for
// the edge-gather table hW) instead of fp32.
template <bool BF16OUT>
__global__ __launch_bounds__(256) void gemm128_kernel(const float* __restrict__ X,
                                                      const float* __restrict__ W,
                                                      const float* __restrict__ bias,
                                                      void* __restrict__ Yv) {
    __shared__ float sw[128 * 128];  // 64 KiB
    {
        const float4* w4 = (const float4*)W;
        float4* s4 = (float4*)sw;
        for (int i = threadIdx.x; i < 128 * 128 / 4; i += 256) s4[i] = w4[i];
    }
    __syncthreads();

    const int tx = threadIdx.x & 15;
    const int ty = threadIdx.x >> 4;
    const int r0 = blockIdx.x * 64 + ty * 4;
    const int cA = tx * 4, cB = 64 + tx * 4;

    float acc[4][8];
#pragma unroll
    for (int i = 0; i < 4; i++)
#pragma unroll
        for (int j = 0; j < 4; j++) {
            float bA = bias ? bias[cA + j] : 0.f;
            float bB = bias ? bias[cB + j] : 0.f;
            acc[i][j] = bA;
            acc[i][4 + j] = bB;
        }

    for (int k = 0; k < 128; k += 4) {
        float4 xv[4];
#pragma unroll
        for (int i = 0; i < 4; i++) {
            int r = r0 + i;
            xv[i] = (r < N_NODES) ? *(const float4*)(X + (size_t)r * 128 + k)
                                  : make_float4(0.f, 0.f, 0.f, 0.f);
        }
#pragma unroll
        for (int kk = 0; kk < 4; kk++) {
            float4 w0 = *(const float4*)(sw + (k + kk) * 128 + cA);
            float4 w1 = *(const float4*)(sw + (k + kk) * 128 + cB);
#pragma unroll
            for (int i = 0; i < 4; i++) {
                float xs = ((const float*)&xv[i])[kk];
                acc[i][0] = fmaf(xs, w0.x, acc[i][0]);
                acc[i][1] = fmaf(xs, w0.y, acc[i][1]);
                acc[i][2] = fmaf(xs, w0.z, acc[i][2]);
                acc[i][3] = fmaf(xs, w0.w, acc[i][3]);
                acc[i][4] = fmaf(xs, w1.x, acc[i][4]);
                acc[i][5] = fmaf(xs, w1.y, acc[i][5]);
                acc[i][6] = fmaf(xs, w1.z, acc[i][6]);
                acc[i][7] = fmaf(xs, w1.w, acc[i][7]);
            }
        }
    }
#pragma unroll
    for (int i = 0; i < 4; i++) {
        int r = r0 + i;
        if (r < N_NODES) {
            if (BF16OUT) {
                unsigned short* Y = (unsigned short*)Yv;
                ushort4 oA = {f2bf(acc[i][0]), f2bf(acc[i][1]), f2bf(acc[i][2]), f2bf(acc[i][3])};
                ushort4 oB = {f2bf(acc[i][4]), f2bf(acc[i][5]), f2bf(acc[i][6]), f2bf(acc[i][7])};
                *(ushort4*)(Y + (size_t)r * 128 + cA) = oA;
                *(ushort4*)(Y + (size_t)r * 128 + cB) = oB;
            } else {
                float* Y = (float*)Yv;
                *(float4*)(Y + (size_t)r * 128 + cA) =
                    make_float4(acc[i][0], acc[i][1], acc[i][2], acc[i][3]);
                *(float4*)(Y + (size_t)r * 128 + cB) =
                    make_float4(acc[i][4], acc[i][5], acc[i][6], acc[i][7]);
            }
        }
    }
}

// ---------------- input proj epilogue: h += label_emb[label] @ W[128:160], relu ----
__global__ __launch_bounds__(256) void add_label_relu_kernel(const int* __restrict__ label,
                                                             const float* __restrict__ label_emb,
                                                             const float* __restrict__ Wl,  // [32][128]
                                                             float* __restrict__ h) {
    __shared__ float sw[LABEL_DIM * 128];  // 16 KiB
    for (int i = threadIdx.x; i < LABEL_DIM * 128; i += 256) sw[i] = Wl[i];
    __syncthreads();
    int idx = blockIdx.x * 256 + threadIdx.x;
    int r = idx >> 7, c = idx & 127;
    int lb = label[r];
    float a = h[idx];
    const float* le = label_emb + (size_t)lb * LABEL_DIM;
#pragma unroll
    for (int k = 0; k < LABEL_DIM; k++) a = fmaf(le[k], sw[k * 128 + c], a);
    h[idx] = fmaxf(a, 0.f);
}

// ---------------- relW[1024,128] (bf16) = rel_emb[l] @ lin_rel_w[l] ----------------
__global__ __launch_bounds__(256) void relw_kernel(const float* __restrict__ rel_emb,  // [1024][32]
                                                   const float* __restrict__ Wr,       // [32][128]
                                                   unsigned short* __restrict__ relW) {
    __shared__ float sw[REL_DIM * 128];
    for (int i = threadIdx.x; i < REL_DIM * 128; i += 256) sw[i] = Wr[i];
    __syncthreads();
    int idx = blockIdx.x * 256 + threadIdx.x;  // 1024*128 total, exact
    int r = idx >> 7, c = idx & 127;
    const float* re = rel_emb + (size_t)r * REL_DIM;
    float a = 0.f;
#pragma unroll
    for (int k = 0; k < REL_DIM; k++) a = fmaf(re[k], sw[k * 128 + c], a);
    relW[idx] = f2bf(a);
}

// ---------------- edge gather + mean + self + relu + layernorm ----------------
// One WAVE per node (4 nodes per 256-thread block). Lane L owns cols 2L,2L+1.
// bf16x2 gather loads (256B/row/wave), shuffle-based LN, no LDS, no syncthreads.
__global__ __launch_bounds__(256) void agg_ln_kernel(const __hip_bfloat162* __restrict__ hW2,
                                                     const __hip_bfloat162* __restrict__ relW2,
                                                     const float* __restrict__ hs,
                                                     const int* __restrict__ offsets,
                                                     const int* __restrict__ csr_src,
                                                     const int* __restrict__ csr_rel,
                                                     const float* __restrict__ g,
                                                     const float* __restrict__ b,
                                                     float* __restrict__ h) {
    int wave = threadIdx.x >> 6;
    int lane = threadIdx.x & 63;
    int node = blockIdx.x * 4 + wave;
    if (node >= N_NODES) return;
    int beg = offsets[node], end = offsets[node + 1];

    float acc0 = 0.f, acc1 = 0.f;
    int e = beg;
    for (; e + 1 < end; e += 2) {
        int s0 = csr_src[e], s1 = csr_src[e + 1];
        int r0 = csr_rel[e], r1 = csr_rel[e + 1];
        __hip_bfloat162 a0 = hW2[(size_t)s0 * 64 + lane];
        __hip_bfloat162 b0 = relW2[(size_t)r0 * 64 + lane];
        __hip_bfloat162 a1 = hW2[(size_t)s1 * 64 + lane];
        __hip_bfloat162 b1 = relW2[(size_t)r1 * 64 + lane];
        acc0 += __bfloat162float(a0.x) + __bfloat162float(b0.x) + __bfloat162float(a1.x) +
                __bfloat162float(b1.x);
        acc1 += __bfloat162float(a0.y) + __bfloat162float(b0.y) + __bfloat162float(a1.y) +
                __bfloat162float(b1.y);
    }
    if (e < end) {
        int s0 = csr_src[e], r0 = csr_rel[e];
        __hip_bfloat162 a0 = hW2[(size_t)s0 * 64 + lane];
        __hip_bfloat162 b0 = relW2[(size_t)r0 * 64 + lane];
        acc0 += __bfloat162float(a0.x) + __bfloat162float(b0.x);
        acc1 += __bfloat162float(a0.y) + __bfloat162float(b0.y);
    }

    float inv = (end > beg) ? 1.f / (float)(end - beg) : 0.f;
    float2 hsv = *(const float2*)(hs + (size_t)node * 128 + 2 * lane);
    float v0 = fmaxf(hsv.x + acc0 * inv, 0.f);
    float v1 = fmaxf(hsv.y + acc1 * inv, 0.f);

    float s = v0 + v1;
#pragma unroll
    for (int o = 32; o > 0; o >>= 1) s += __shfl_xor(s, o, 64);
    float mu = s * (1.f / 128.f);
    float d0 = v0 - mu, d1 = v1 - mu;
    float q = d0 * d0 + d1 * d1;
#pragma unroll
    for (int o = 32; o > 0; o >>= 1) q += __shfl_xor(q, o, 64);
    float rstd = rsqrtf(q * (1.f / 128.f) + LN_EPS);

    float2 gv = *(const float2*)(g + 2 * lane);
    float2 bv = *(const float2*)(b + 2 * lane);
    float2 out = make_float2(d0 * rstd * gv.x + bv.x, d1 * rstd * gv.y + bv.y);
    *(float2*)(h + (size_t)node * 128 + 2 * lane) = out;
}

// ---------------- launch ----------------

extern "C" void kernel_launch(void* const* d_in, const int* in_sizes, int n_in,
                              void* d_out, int out_size, void* d_ws, size_t ws_size,
                              hipStream_t stream) {
    const float* x          = (const float*)d_in[0];
    const int*   label      = (const int*)d_in[1];
    const int*   edge_index = (const int*)d_in[2];
    const int*   edge_rel   = (const int*)d_in[3];
    const float* label_emb  = (const float*)d_in[4];
    const float* in_proj_w  = (const float*)d_in[5];
    const float* in_proj_b  = (const float*)d_in[6];
    const float* rel_emb    = (const float*)d_in[7];
    const float* lin_neigh_w = (const float*)d_in[8];
    const float* lin_self_w  = (const float*)d_in[9];
    const float* lin_self_b  = (const float*)d_in[10];
    const float* lin_rel_w   = (const float*)d_in[11];
    const float* ln_g        = (const float*)d_in[12];
    const float* ln_b        = (const float*)d_in[13];
    float* h = (float*)d_out;

    char* p = (char*)d_ws;
    auto alloc = [&](size_t bytes) {
        char* r = p;
        p += (bytes + 255) & ~(size_t)255;
        return r;
    };
    int* deg       = (int*)alloc((size_t)N_NODES * 4);
    int* offsets   = (int*)alloc((size_t)(N_NODES + 1) * 4);
    int* cursor    = (int*)alloc((size_t)N_NODES * 4);
    int* blockSums = (int*)alloc((size_t)N_SCAN_BLOCKS * 4);
    int* csr_src   = (int*)alloc((size_t)N_EDGES * 4);
    int* csr_rel   = (int*)alloc((size_t)N_EDGES * 4);
    unsigned short* hW   = (unsigned short*)alloc((size_t)N_NODES * 128 * 2);
    float*          hs   = (float*)alloc((size_t)N_NODES * 128 * 4);
    unsigned short* relW = (unsigned short*)alloc((size_t)REL_BUCKETS * 128 * 2);

    const int* src = edge_index;
    const int* dst = edge_index + N_EDGES;

    // CSR build
    hipMemsetAsync(deg, 0, (size_t)N_NODES * 4, stream);
    count_deg_kernel<<<(N_EDGES + 255) / 256, 256, 0, stream>>>(dst, deg);
    scan_tiles_kernel<<<N_SCAN_BLOCKS, SCAN_TILE, 0, stream>>>(deg, offsets, blockSums);
    scan_sums_kernel<<<1, 64, 0, stream>>>(blockSums, offsets);
    scan_add_kernel<<<N_SCAN_BLOCKS, SCAN_TILE, 0, stream>>>(offsets, blockSums, cursor);
    fill_csr_kernel<<<(N_EDGES + 255) / 256, 256, 0, stream>>>(src, dst, edge_rel, cursor,
                                                               csr_src, csr_rel);

    // input projection: h = relu(x @ W[:128] + label_emb[label] @ W[128:] + b)
    gemm128_kernel<false><<<(N_NODES + 63) / 64, 256, 0, stream>>>(x, in_proj_w, in_proj_b, h);
    add_label_relu_kernel<<<(N_NODES * 128) / 256, 256, 0, stream>>>(
        label, label_emb, in_proj_w + 128 * 128, h);

    for (int l = 0; l < 2; l++) {
        relw_kernel<<<(REL_BUCKETS * 128) / 256, 256, 0, stream>>>(
            rel_emb + (size_t)l * REL_BUCKETS * REL_DIM, lin_rel_w + (size_t)l * REL_DIM * 128,
            relW);
        gemm128_kernel<true><<<(N_NODES + 63) / 64, 256, 0, stream>>>(
            h, lin_neigh_w + (size_t)l * 128 * 128, nullptr, hW);
        gemm128_kernel<false><<<(N_NODES + 63) / 64, 256, 0, stream>>>(
            h, lin_self_w + (size_t)l * 128 * 128, lin_self_b + (size_t)l * 128, hs);
        agg_ln_kernel<<<(N_NODES + 3) / 4, 256, 0, stream>>>(
            (const __hip_bfloat162*)hW, (const __hip_bfloat162*)relW, hs, offsets, csr_src,
            csr_rel, ln_g + (size_t)l * 128, ln_b + (size_t)l * 128, h);
    }
}

// Round 3
// 441.816 us; speedup vs baseline: 1.7896x; 1.5811x over previous
//
#include <hip/hip_runtime.h>
#include <hip/hip_bf16.h>

#define N_NODES 50000
#define N_EDGES 800000
#define D 128
#define LABEL_DIM 32
#define REL_DIM 32
#define REL_BUCKETS 1024
#define LN_EPS 1e-5f

#define SCAN_TILE 1024
#define N_SCAN_BLOCKS ((N_NODES + SCAN_TILE - 1) / SCAN_TILE)  // 49

typedef short bf16x8 __attribute__((ext_vector_type(8)));
typedef float f32x4 __attribute__((ext_vector_type(4)));

__device__ inline unsigned short f2bf(float f) {
    __hip_bfloat16 h = __float2bfloat16(f);
    return *reinterpret_cast<unsigned short*>(&h);
}

// ---------------- CSR build ----------------

__global__ __launch_bounds__(256) void count_deg_kernel(const int* __restrict__ dst,
                                                        int* __restrict__ deg) {
    int e = blockIdx.x * 256 + threadIdx.x;
    if (e < N_EDGES) atomicAdd(&deg[dst[e]], 1);
}

__global__ __launch_bounds__(SCAN_TILE) void scan_tiles_kernel(const int* __restrict__ deg,
                                                               int* __restrict__ offsets,
                                                               int* __restrict__ blockSums) {
    __shared__ int buf[SCAN_TILE];
    int i = blockIdx.x * SCAN_TILE + threadIdx.x;
    int v = (i < N_NODES) ? deg[i] : 0;
    buf[threadIdx.x] = v;
    __syncthreads();
    for (int off = 1; off < SCAN_TILE; off <<= 1) {
        int t = (threadIdx.x >= (unsigned)off) ? buf[threadIdx.x - off] : 0;
        __syncthreads();
        buf[threadIdx.x] += t;
        __syncthreads();
    }
    if (i < N_NODES) offsets[i] = buf[threadIdx.x] - v;
    if (threadIdx.x == SCAN_TILE - 1) blockSums[blockIdx.x] = buf[SCAN_TILE - 1];
}

__global__ void scan_sums_kernel(int* __restrict__ blockSums, int* __restrict__ offsets) {
    if (threadIdx.x == 0 && blockIdx.x == 0) {
        int run = 0;
        for (int i = 0; i < N_SCAN_BLOCKS; i++) {
            int v = blockSums[i];
            blockSums[i] = run;
            run += v;
        }
        offsets[N_NODES] = run;
    }
}

__global__ __launch_bounds__(SCAN_TILE) void scan_add_kernel(int* __restrict__ offsets,
                                                             const int* __restrict__ blockSums,
                                                             int* __restrict__ cursor) {
    int i = blockIdx.x * SCAN_TILE + threadIdx.x;
    if (i < N_NODES) {
        int o = offsets[i] + blockSums[blockIdx.x];
        offsets[i] = o;
        cursor[i] = o;
    }
}

__global__ __launch_bounds__(256) void fill_csr_kernel(const int* __restrict__ src,
                                                       const int* __restrict__ dst,
                                                       const int* __restrict__ rel,
                                                       int* __restrict__ cursor,
                                                       int* __restrict__ csr_src,
                                                       int* __restrict__ csr_rel) {
    int e = blockIdx.x * 256 + threadIdx.x;
    if (e < N_EDGES) {
        int d = dst[e];
        int pos = atomicAdd(&cursor[d], 1);
        csr_src[pos] = src[e];
        csr_rel[pos] = rel[e];
    }
}

// ---------------- weight prep ----------------
// Bt[n][k] (bf16) = W[k][n] (fp32); dual packs [Wn | Ws] into 256 cols.
__global__ __launch_bounds__(256) void prep_dual_kernel(const float* __restrict__ Wn,
                                                        const float* __restrict__ Ws,
                                                        unsigned short* __restrict__ Bt) {
    int idx = blockIdx.x * 256 + threadIdx.x;  // 256*128 exact
    int n = idx >> 7, k = idx & 127;
    float v = (n < 128) ? Wn[k * 128 + n] : Ws[k * 128 + (n - 128)];
    Bt[idx] = f2bf(v);
}

__global__ __launch_bounds__(256) void prep_single_kernel(const float* __restrict__ W,
                                                          unsigned short* __restrict__ Bt) {
    int idx = blockIdx.x * 256 + threadIdx.x;  // 128*128 exact
    int n = idx >> 7, k = idx & 127;
    Bt[idx] = f2bf(W[k * 128 + n]);
}

__global__ __launch_bounds__(256) void f32_to_bf16_kernel(const float* __restrict__ x,
                                                          unsigned short* __restrict__ xb) {
    int i = blockIdx.x * 256 + threadIdx.x;  // N*128/4 exact
    float4 v = ((const float4*)x)[i];
    ushort4 o = {f2bf(v.x), f2bf(v.y), f2bf(v.z), f2bf(v.w)};
    ((ushort4*)xb)[i] = o;
}

// ---------------- MFMA GEMM ----------------
// A [N,128] bf16 row-major. Bt [NT*16][128] bf16 (N-major). 256 thr = 4 waves,
// 64 rows/block, wave computes 16 rows x NT*16 cols via 16x16x32 MFMA.
// DUAL: col tiles 0-7 -> bf16 outBF, tiles 8-15 -> fp32 outF + bias.
// LDS holds Bt XOR-swizzled: chunk(col,kch) = col*16 + (kch ^ (col&7)); 16B chunks.
template <int NT, bool DUAL>
__global__ __launch_bounds__(256) void mfma_gemm_kernel(const unsigned short* __restrict__ A,
                                                        const unsigned short* __restrict__ Bt,
                                                        const float* __restrict__ bias,
                                                        unsigned short* __restrict__ outBF,
                                                        float* __restrict__ outF) {
    __shared__ unsigned short sB[NT * 16 * 128];  // NT=16 -> 64 KiB
    const int t = threadIdx.x;
#pragma unroll
    for (int i = 0; i < NT; ++i) {  // NT*256 chunks / 256 threads... (NT*16*16/256 = NT)
        int c = t + i * 256;
        int col = c >> 4, kch = c & 15;
        int dstc = col * 16 + (kch ^ (col & 7));
        *(bf16x8*)&sB[dstc * 8] = *(const bf16x8*)&Bt[c * 8];
    }
    __syncthreads();

    const int wave = t >> 6, lane = t & 63;
    const int m16 = lane & 15, q = lane >> 4;
    const int r0 = blockIdx.x * 64 + wave * 16;
    const int arow = r0 + m16;
    const bool avalid = arow < N_NODES;
    const unsigned short* ap = A + (size_t)(avalid ? arow : 0) * 128 + q * 8;

    f32x4 acc[NT];
#pragma unroll
    for (int ct = 0; ct < NT; ++ct) acc[ct] = (f32x4){0.f, 0.f, 0.f, 0.f};

#pragma unroll
    for (int ki = 0; ki < 4; ++ki) {
        bf16x8 af = *(const bf16x8*)(ap + ki * 32);
        if (!avalid) af = (bf16x8){0, 0, 0, 0, 0, 0, 0, 0};
        int kch = ki * 4 + q;
#pragma unroll
        for (int ct = 0; ct < NT; ++ct) {
            int col = ct * 16 + m16;
            int chunk = col * 16 + (kch ^ (m16 & 7));
            bf16x8 bf = *(const bf16x8*)&sB[chunk * 8];
            acc[ct] = __builtin_amdgcn_mfma_f32_16x16x32_bf16(af, bf, acc[ct], 0, 0, 0);
        }
    }

    // D: row = r0 + q*4 + reg, col = ct*16 + m16
#pragma unroll
    for (int ct = 0; ct < NT; ++ct) {
        int colg = ct * 16 + m16;
#pragma unroll
        for (int r = 0; r < 4; ++r) {
            int row = r0 + q * 4 + r;
            if (row < N_NODES) {
                float v = acc[ct][r];
                if (DUAL) {
                    if (ct < 8)
                        outBF[(size_t)row * 128 + colg] = f2bf(v);
                    else
                        outF[(size_t)row * 128 + (colg - 128)] = v + bias[colg - 128];
                } else {
                    outF[(size_t)row * 128 + colg] = v + bias[colg];
                }
            }
        }
    }
}

// ---------------- input proj epilogue: h += label_emb[label] @ W[128:160], relu ----
__global__ __launch_bounds__(256) void add_label_relu_kernel(const int* __restrict__ label,
                                                             const float* __restrict__ label_emb,
                                                             const float* __restrict__ Wl,
                                                             float* __restrict__ h,
                                                             unsigned short* __restrict__ hb) {
    __shared__ float sw[LABEL_DIM * 128];  // 16 KiB
    for (int i = threadIdx.x; i < LABEL_DIM * 128; i += 256) sw[i] = Wl[i];
    __syncthreads();
    int idx = blockIdx.x * 256 + threadIdx.x;
    int r = idx >> 7, c = idx & 127;
    int lb = label[r];
    float a = h[idx];
    const float* le = label_emb + (size_t)lb * LABEL_DIM;
#pragma unroll
    for (int k = 0; k < LABEL_DIM; k++) a = fmaf(le[k], sw[k * 128 + c], a);
    a = fmaxf(a, 0.f);
    h[idx] = a;
    hb[idx] = f2bf(a);
}

// ---------------- relW[1024,128] (bf16) = rel_emb[l] @ lin_rel_w[l] ----------------
__global__ __launch_bounds__(256) void relw_kernel(const float* __restrict__ rel_emb,
                                                   const float* __restrict__ Wr,
                                                   unsigned short* __restrict__ relW) {
    __shared__ float sw[REL_DIM * 128];
    for (int i = threadIdx.x; i < REL_DIM * 128; i += 256) sw[i] = Wr[i];
    __syncthreads();
    int idx = blockIdx.x * 256 + threadIdx.x;  // 1024*128 exact
    int r = idx >> 7, c = idx & 127;
    const float* re = rel_emb + (size_t)r * REL_DIM;
    float a = 0.f;
#pragma unroll
    for (int k = 0; k < REL_DIM; k++) a = fmaf(re[k], sw[k * 128 + c], a);
    relW[idx] = f2bf(a);
}

// ---------------- edge gather + mean + self + relu + layernorm ----------------
// One wave per node; lane L owns cols 2L, 2L+1. Writes fp32 h and bf16 hb.
__global__ __launch_bounds__(256) void agg_ln_kernel(const __hip_bfloat162* __restrict__ hW2,
                                                     const __hip_bfloat162* __restrict__ relW2,
                                                     const float* __restrict__ hs,
                                                     const int* __restrict__ offsets,
                                                     const int* __restrict__ csr_src,
                                                     const int* __restrict__ csr_rel,
                                                     const float* __restrict__ g,
                                                     const float* __restrict__ b,
                                                     float* __restrict__ h,
                                                     unsigned short* __restrict__ hb) {
    int wave = threadIdx.x >> 6;
    int lane = threadIdx.x & 63;
    int node = blockIdx.x * 4 + wave;
    if (node >= N_NODES) return;
    int beg = offsets[node], end = offsets[node + 1];

    float acc0 = 0.f, acc1 = 0.f;
    int e = beg;
    for (; e + 1 < end; e += 2) {
        int s0 = csr_src[e], s1 = csr_src[e + 1];
        int r0 = csr_rel[e], r1 = csr_rel[e + 1];
        __hip_bfloat162 a0 = hW2[(size_t)s0 * 64 + lane];
        __hip_bfloat162 b0 = relW2[(size_t)r0 * 64 + lane];
        __hip_bfloat162 a1 = hW2[(size_t)s1 * 64 + lane];
        __hip_bfloat162 b1 = relW2[(size_t)r1 * 64 + lane];
        acc0 += __bfloat162float(a0.x) + __bfloat162float(b0.x) + __bfloat162float(a1.x) +
                __bfloat162float(b1.x);
        acc1 += __bfloat162float(a0.y) + __bfloat162float(b0.y) + __bfloat162float(a1.y) +
                __bfloat162float(b1.y);
    }
    if (e < end) {
        int s0 = csr_src[e], r0 = csr_rel[e];
        __hip_bfloat162 a0 = hW2[(size_t)s0 * 64 + lane];
        __hip_bfloat162 b0 = relW2[(size_t)r0 * 64 + lane];
        acc0 += __bfloat162float(a0.x) + __bfloat162float(b0.x);
        acc1 += __bfloat162float(a0.y) + __bfloat162float(b0.y);
    }

    float inv = (end > beg) ? 1.f / (float)(end - beg) : 0.f;
    float2 hsv = *(const float2*)(hs + (size_t)node * 128 + 2 * lane);
    float v0 = fmaxf(hsv.x + acc0 * inv, 0.f);
    float v1 = fmaxf(hsv.y + acc1 * inv, 0.f);

    float s = v0 + v1;
#pragma unroll
    for (int o = 32; o > 0; o >>= 1) s += __shfl_xor(s, o, 64);
    float mu = s * (1.f / 128.f);
    float d0 = v0 - mu, d1 = v1 - mu;
    float q = d0 * d0 + d1 * d1;
#pragma unroll
    for (int o = 32; o > 0; o >>= 1) q += __shfl_xor(q, o, 64);
    float rstd = rsqrtf(q * (1.f / 128.f) + LN_EPS);

    float2 gv = *(const float2*)(g + 2 * lane);
    float2 bv = *(const float2*)(b + 2 * lane);
    float o0 = d0 * rstd * gv.x + bv.x;
    float o1 = d1 * rstd * gv.y + bv.y;
    *(float2*)(h + (size_t)node * 128 + 2 * lane) = make_float2(o0, o1);
    ushort2 ob = {f2bf(o0), f2bf(o1)};
    *(ushort2*)(hb + (size_t)node * 128 + 2 * lane) = ob;
}

// ---------------- launch ----------------

extern "C" void kernel_launch(void* const* d_in, const int* in_sizes, int n_in,
                              void* d_out, int out_size, void* d_ws, size_t ws_size,
                              hipStream_t stream) {
    const float* x          = (const float*)d_in[0];
    const int*   label      = (const int*)d_in[1];
    const int*   edge_index = (const int*)d_in[2];
    const int*   edge_rel   = (const int*)d_in[3];
    const float* label_emb  = (const float*)d_in[4];
    const float* in_proj_w  = (const float*)d_in[5];
    const float* in_proj_b  = (const float*)d_in[6];
    const float* rel_emb    = (const float*)d_in[7];
    const float* lin_neigh_w = (const float*)d_in[8];
    const float* lin_self_w  = (const float*)d_in[9];
    const float* lin_self_b  = (const float*)d_in[10];
    const float* lin_rel_w   = (const float*)d_in[11];
    const float* ln_g        = (const float*)d_in[12];
    const float* ln_b        = (const float*)d_in[13];
    float* h = (float*)d_out;

    char* p = (char*)d_ws;
    auto alloc = [&](size_t bytes) {
        char* r = p;
        p += (bytes + 255) & ~(size_t)255;
        return r;
    };
    int* deg       = (int*)alloc((size_t)N_NODES * 4);
    int* offsets   = (int*)alloc((size_t)(N_NODES + 1) * 4);
    int* cursor    = (int*)alloc((size_t)N_NODES * 4);
    int* blockSums = (int*)alloc((size_t)N_SCAN_BLOCKS * 4);
    int* csr_src   = (int*)alloc((size_t)N_EDGES * 4);
    int* csr_rel   = (int*)alloc((size_t)N_EDGES * 4);
    unsigned short* hW   = (unsigned short*)alloc((size_t)N_NODES * 128 * 2);
    float*          hs   = (float*)alloc((size_t)N_NODES * 128 * 4);
    unsigned short* relW = (unsigned short*)alloc((size_t)REL_BUCKETS * 128 * 2);
    unsigned short* hb   = (unsigned short*)alloc((size_t)N_NODES * 128 * 2);  // x_bf aliases hb
    unsigned short* Bt   = (unsigned short*)alloc((size_t)256 * 128 * 2);

    const int* src = edge_index;
    const int* dst = edge_index + N_EDGES;

    // CSR build
    hipMemsetAsync(deg, 0, (size_t)N_NODES * 4, stream);
    count_deg_kernel<<<(N_EDGES + 255) / 256, 256, 0, stream>>>(dst, deg);
    scan_tiles_kernel<<<N_SCAN_BLOCKS, SCAN_TILE, 0, stream>>>(deg, offsets, blockSums);
    scan_sums_kernel<<<1, 64, 0, stream>>>(blockSums, offsets);
    scan_add_kernel<<<N_SCAN_BLOCKS, SCAN_TILE, 0, stream>>>(offsets, blockSums, cursor);
    fill_csr_kernel<<<(N_EDGES + 255) / 256, 256, 0, stream>>>(src, dst, edge_rel, cursor,
                                                               csr_src, csr_rel);

    const int gemm_grid = (N_NODES + 63) / 64;  // 782

    // input projection: h = relu(x @ W[:128] + label_emb[label] @ W[128:] + b)
    f32_to_bf16_kernel<<<(N_NODES * 128 / 4) / 256, 256, 0, stream>>>(x, hb);  // hb = x_bf
    prep_single_kernel<<<(128 * 128) / 256, 256, 0, stream>>>(in_proj_w, Bt);
    mfma_gemm_kernel<8, false><<<gemm_grid, 256, 0, stream>>>(hb, Bt, in_proj_b, nullptr, h);
    add_label_relu_kernel<<<(N_NODES * 128) / 256, 256, 0, stream>>>(
        label, label_emb, in_proj_w + 128 * 128, h, hb);

    for (int l = 0; l < 2; l++) {
        relw_kernel<<<(REL_BUCKETS * 128) / 256, 256, 0, stream>>>(
            rel_emb + (size_t)l * REL_BUCKETS * REL_DIM, lin_rel_w + (size_t)l * REL_DIM * 128,
            relW);
        prep_dual_kernel<<<(256 * 128) / 256, 256, 0, stream>>>(
            lin_neigh_w + (size_t)l * 128 * 128, lin_self_w + (size_t)l * 128 * 128, Bt);
        mfma_gemm_kernel<16, true><<<gemm_grid, 256, 0, stream>>>(
            hb, Bt, lin_self_b + (size_t)l * 128, hW, hs);
        agg_ln_kernel<<<(N_NODES + 3) / 4, 256, 0, stream>>>(
            (const __hip_bfloat162*)hW, (const __hip_bfloat162*)relW, hs, offsets, csr_src,
            csr_rel, ln_g + (size_t)l * 128, ln_b + (size_t)l * 128, h, hb);
    }
}

// Round 4
// 390.987 us; speedup vs baseline: 2.0223x; 1.1300x over previous
//
#include <hip/hip_runtime.h>
#include <hip/hip_bf16.h>

#define N_NODES 50000
#define N_EDGES 800000
#define D 128
#define LABEL_DIM 32
#define REL_DIM 32
#define REL_BUCKETS 1024
#define NUM_LABELS 1000
#define LN_EPS 1e-5f

#define SCAN_TILE 1024
#define N_SCAN_BLOCKS ((N_NODES + SCAN_TILE - 1) / SCAN_TILE)  // 49

typedef short bf16x8 __attribute__((ext_vector_type(8)));
typedef float f32x4 __attribute__((ext_vector_type(4)));

__device__ inline unsigned short f2bf(float f) {
    __hip_bfloat16 h = __float2bfloat16(f);
    return *reinterpret_cast<unsigned short*>(&h);
}
__device__ inline float bf2f(unsigned short u) {
    return __uint_as_float((unsigned)u << 16);
}

// ---------------- CSR build ----------------

__global__ __launch_bounds__(256) void count_deg_kernel(const int* __restrict__ dst,
                                                        int* __restrict__ deg) {
    int e = blockIdx.x * 256 + threadIdx.x;
    if (e < N_EDGES) atomicAdd(&deg[dst[e]], 1);
}

__global__ __launch_bounds__(SCAN_TILE) void scan_tiles_kernel(const int* __restrict__ deg,
                                                               int* __restrict__ offsets,
                                                               int* __restrict__ blockSums) {
    __shared__ int buf[SCAN_TILE];
    int i = blockIdx.x * SCAN_TILE + threadIdx.x;
    int v = (i < N_NODES) ? deg[i] : 0;
    buf[threadIdx.x] = v;
    __syncthreads();
    for (int off = 1; off < SCAN_TILE; off <<= 1) {
        int t = (threadIdx.x >= (unsigned)off) ? buf[threadIdx.x - off] : 0;
        __syncthreads();
        buf[threadIdx.x] += t;
        __syncthreads();
    }
    if (i < N_NODES) offsets[i] = buf[threadIdx.x] - v;
    if (threadIdx.x == SCAN_TILE - 1) blockSums[blockIdx.x] = buf[SCAN_TILE - 1];
}

__global__ void scan_sums_kernel(int* __restrict__ blockSums, int* __restrict__ offsets) {
    if (threadIdx.x == 0 && blockIdx.x == 0) {
        int run = 0;
        for (int i = 0; i < N_SCAN_BLOCKS; i++) {
            int v = blockSums[i];
            blockSums[i] = run;
            run += v;
        }
        offsets[N_NODES] = run;
    }
}

__global__ __launch_bounds__(SCAN_TILE) void scan_add_kernel(int* __restrict__ offsets,
                                                             const int* __restrict__ blockSums,
                                                             int* __restrict__ cursor) {
    int i = blockIdx.x * SCAN_TILE + threadIdx.x;
    if (i < N_NODES) {
        int o = offsets[i] + blockSums[blockIdx.x];
        offsets[i] = o;
        cursor[i] = o;
    }
}

__global__ __launch_bounds__(256) void fill_csr_kernel(const int* __restrict__ src,
                                                       const int* __restrict__ dst,
                                                       const int* __restrict__ rel,
                                                       int* __restrict__ cursor,
                                                       int* __restrict__ csr_src,
                                                       int* __restrict__ csr_rel) {
    int e = blockIdx.x * 256 + threadIdx.x;
    if (e < N_EDGES) {
        int d = dst[e];
        int pos = atomicAdd(&cursor[d], 1);
        csr_src[pos] = src[e];
        csr_rel[pos] = rel[e];
    }
}

// ---------------- weight / embedding prep ----------------

__global__ __launch_bounds__(256) void prep_dual_kernel(const float* __restrict__ Wn,
                                                        const float* __restrict__ Ws,
                                                        unsigned short* __restrict__ Bt) {
    int idx = blockIdx.x * 256 + threadIdx.x;  // 256*128 exact
    int n = idx >> 7, k = idx & 127;
    float v = (n < 128) ? Wn[k * 128 + n] : Ws[k * 128 + (n - 128)];
    Bt[idx] = f2bf(v);
}

// Btx[n][k] = in_proj_w[k][n], n<128, k<160
__global__ __launch_bounds__(256) void prep_in_kernel(const float* __restrict__ W,
                                                      unsigned short* __restrict__ Btx) {
    int idx = blockIdx.x * 256 + threadIdx.x;  // 128*160 = 20480 exact
    int n = idx / 160, k = idx % 160;
    Btx[idx] = f2bf(W[k * 128 + n]);
}

__global__ __launch_bounds__(256) void prep_lemb_kernel(const float* __restrict__ le,
                                                        unsigned short* __restrict__ leb) {
    int i = blockIdx.x * 256 + threadIdx.x;  // 32000 total
    if (i < NUM_LABELS * LABEL_DIM) leb[i] = f2bf(le[i]);
}

__global__ __launch_bounds__(256) void f32_to_bf16_kernel(const float* __restrict__ x,
                                                          unsigned short* __restrict__ xb) {
    int i = blockIdx.x * 256 + threadIdx.x;  // N*128/4 exact
    float4 v = ((const float4*)x)[i];
    ushort4 o = {f2bf(v.x), f2bf(v.y), f2bf(v.z), f2bf(v.w)};
    ((ushort4*)xb)[i] = o;
}

// ---------------- dual MFMA GEMM: [hW(bf16) | hs(f32)+bias] = hb @ [Wn|Ws] ----
__global__ __launch_bounds__(256) void mfma_dual_kernel(const unsigned short* __restrict__ A,
                                                        const unsigned short* __restrict__ Bt,
                                                        const float* __restrict__ bias,
                                                        unsigned short* __restrict__ outBF,
                                                        float* __restrict__ outF) {
    __shared__ unsigned short sB[256 * 128];  // 64 KiB
    const int t = threadIdx.x;
#pragma unroll
    for (int i = 0; i < 16; ++i) {
        int c = t + i * 256;
        int col = c >> 4, kch = c & 15;
        int dstc = col * 16 + (kch ^ (col & 7));
        *(bf16x8*)&sB[dstc * 8] = *(const bf16x8*)&Bt[c * 8];
    }
    __syncthreads();

    const int wave = t >> 6, lane = t & 63;
    const int m16 = lane & 15, q = lane >> 4;
    const int r0 = blockIdx.x * 64 + wave * 16;
    const int arow = r0 + m16;
    const bool avalid = arow < N_NODES;
    const unsigned short* ap = A + (size_t)(avalid ? arow : 0) * 128 + q * 8;

    f32x4 acc[16];
#pragma unroll
    for (int ct = 0; ct < 16; ++ct) acc[ct] = (f32x4){0.f, 0.f, 0.f, 0.f};

#pragma unroll
    for (int ki = 0; ki < 4; ++ki) {
        bf16x8 af = *(const bf16x8*)(ap + ki * 32);
        if (!avalid) af = (bf16x8){0, 0, 0, 0, 0, 0, 0, 0};
        int kch = ki * 4 + q;
#pragma unroll
        for (int ct = 0; ct < 16; ++ct) {
            int col = ct * 16 + m16;
            int chunk = col * 16 + (kch ^ (m16 & 7));
            bf16x8 bf = *(const bf16x8*)&sB[chunk * 8];
            acc[ct] = __builtin_amdgcn_mfma_f32_16x16x32_bf16(af, bf, acc[ct], 0, 0, 0);
        }
    }

#pragma unroll
    for (int ct = 0; ct < 16; ++ct) {
        int colg = ct * 16 + m16;
#pragma unroll
        for (int r = 0; r < 4; ++r) {
            int row = r0 + q * 4 + r;
            if (row < N_NODES) {
                float v = acc[ct][r];
                if (ct < 8)
                    outBF[(size_t)row * 128 + colg] = f2bf(v);
                else
                    outF[(size_t)row * 128 + (colg - 128)] = v + bias[colg - 128];
            }
        }
    }
}

// ---------------- input-proj MFMA GEMM (K=160, fused label emb + bias + relu) ----
// hb_out = relu([x_bf, lemb_bf[label]] @ in_proj_w + b), bf16. In-place safe:
// each block reads/writes only its own 64-row band.
__global__ __launch_bounds__(256) void mfma_in_kernel(const unsigned short* __restrict__ A,
                                                      const unsigned short* __restrict__ Btx,
                                                      const unsigned short* __restrict__ leb,
                                                      const int* __restrict__ label,
                                                      const float* __restrict__ bias,
                                                      unsigned short* __restrict__ outBF) {
    __shared__ unsigned short sB[128 * 160];  // 40 KiB; [col][20 chunks of 8]
    const int t = threadIdx.x;
#pragma unroll
    for (int i = 0; i < 10; ++i) {
        int c = t + i * 256;  // 2560 chunks
        int col = c / 20, kch = c % 20;
        int dstc = col * 20 + (kch < 16 ? (kch ^ (col & 7)) : kch);
        *(bf16x8*)&sB[dstc * 8] = *(const bf16x8*)&Btx[c * 8];
    }
    __syncthreads();

    const int wave = t >> 6, lane = t & 63;
    const int m16 = lane & 15, q = lane >> 4;
    const int r0 = blockIdx.x * 64 + wave * 16;
    const int arow = r0 + m16;
    const bool avalid = arow < N_NODES;
    const unsigned short* ap = A + (size_t)(avalid ? arow : 0) * 128 + q * 8;

    f32x4 acc[8];
#pragma unroll
    for (int ct = 0; ct < 8; ++ct) acc[ct] = (f32x4){0.f, 0.f, 0.f, 0.f};

#pragma unroll
    for (int ki = 0; ki < 4; ++ki) {
        bf16x8 af = *(const bf16x8*)(ap + ki * 32);
        if (!avalid) af = (bf16x8){0, 0, 0, 0, 0, 0, 0, 0};
        int kch = ki * 4 + q;
#pragma unroll
        for (int ct = 0; ct < 8; ++ct) {
            int col = ct * 16 + m16;
            int chunk = col * 20 + (kch ^ (m16 & 7));
            bf16x8 bf = *(const bf16x8*)&sB[chunk * 8];
            acc[ct] = __builtin_amdgcn_mfma_f32_16x16x32_bf16(af, bf, acc[ct], 0, 0, 0);
        }
    }
    {   // label-embedding K-chunk (k = 128..159)
        int lb = avalid ? label[arow] : 0;
        bf16x8 af = *(const bf16x8*)(leb + (size_t)lb * LABEL_DIM + q * 8);
        if (!avalid) af = (bf16x8){0, 0, 0, 0, 0, 0, 0, 0};
        int kch = 16 + q;
#pragma unroll
        for (int ct = 0; ct < 8; ++ct) {
            int col = ct * 16 + m16;
            int chunk = col * 20 + kch;
            bf16x8 bf = *(const bf16x8*)&sB[chunk * 8];
            acc[ct] = __builtin_amdgcn_mfma_f32_16x16x32_bf16(af, bf, acc[ct], 0, 0, 0);
        }
    }

#pragma unroll
    for (int ct = 0; ct < 8; ++ct) {
        int colg = ct * 16 + m16;
#pragma unroll
        for (int r = 0; r < 4; ++r) {
            int row = r0 + q * 4 + r;
            if (row < N_NODES) {
                float v = fmaxf(acc[ct][r] + bias[colg], 0.f);
                outBF[(size_t)row * 128 + colg] = f2bf(v);
            }
        }
    }
}

// ---------------- relW[1024,128] (bf16) = rel_emb[l] @ lin_rel_w[l] ----------------
__global__ __launch_bounds__(256) void relw_kernel(const float* __restrict__ rel_emb,
                                                   const float* __restrict__ Wr,
                                                   unsigned short* __restrict__ relW) {
    __shared__ float sw[REL_DIM * 128];
    for (int i = threadIdx.x; i < REL_DIM * 128; i += 256) sw[i] = Wr[i];
    __syncthreads();
    int idx = blockIdx.x * 256 + threadIdx.x;  // 1024*128 exact
    int r = idx >> 7, c = idx & 127;
    const float* re = rel_emb + (size_t)r * REL_DIM;
    float a = 0.f;
#pragma unroll
    for (int k = 0; k < REL_DIM; k++) a = fmaf(re[k], sw[k * 128 + c], a);
    relW[idx] = f2bf(a);
}

// ---------------- edge gather + mean + self + relu + layernorm ----------------
// One wave per node. Lanes 0-31 process even edges, 32-63 odd edges; each lane
// loads ushort4 (8B) = 4 cols. Halves combined via shfl_xor(.,32); LN reduces
// within 32-lane halves. Dead outputs templated out (l0: no f32 h; l1: no hb).
template <bool WF32, bool WBF16>
__global__ __launch_bounds__(256) void agg_ln_kernel(const unsigned short* __restrict__ hW,
                                                     const unsigned short* __restrict__ relW,
                                                     const float* __restrict__ hs,
                                                     const int* __restrict__ offsets,
                                                     const int* __restrict__ csr_src,
                                                     const int* __restrict__ csr_rel,
                                                     const float* __restrict__ g,
                                                     const float* __restrict__ b,
                                                     float* __restrict__ h,
                                                     unsigned short* __restrict__ hb) {
    const int wave = threadIdx.x >> 6;
    const int lane = threadIdx.x & 63;
    const int node = blockIdx.x * 4 + wave;
    if (node >= N_NODES) return;
    const int half = lane >> 5, l32 = lane & 31;
    const int beg = offsets[node], end = offsets[node + 1];

    float a0 = 0.f, a1 = 0.f, a2 = 0.f, a3 = 0.f;
    int e = beg;
    for (; e + 1 < end; e += 2) {
        int idx = e + half;
        int s = csr_src[idx];
        int r = csr_rel[idx];
        ushort4 hv = *(const ushort4*)(hW + ((unsigned)s << 7) + (l32 << 2));
        ushort4 rv = *(const ushort4*)(relW + ((unsigned)r << 7) + (l32 << 2));
        a0 += bf2f(hv.x) + bf2f(rv.x);
        a1 += bf2f(hv.y) + bf2f(rv.y);
        a2 += bf2f(hv.z) + bf2f(rv.z);
        a3 += bf2f(hv.w) + bf2f(rv.w);
    }
    if (e < end && half == 0) {
        int s = csr_src[e];
        int r = csr_rel[e];
        ushort4 hv = *(const ushort4*)(hW + ((unsigned)s << 7) + (l32 << 2));
        ushort4 rv = *(const ushort4*)(relW + ((unsigned)r << 7) + (l32 << 2));
        a0 += bf2f(hv.x) + bf2f(rv.x);
        a1 += bf2f(hv.y) + bf2f(rv.y);
        a2 += bf2f(hv.z) + bf2f(rv.z);
        a3 += bf2f(hv.w) + bf2f(rv.w);
    }
    a0 += __shfl_xor(a0, 32);
    a1 += __shfl_xor(a1, 32);
    a2 += __shfl_xor(a2, 32);
    a3 += __shfl_xor(a3, 32);

    float inv = (end > beg) ? 1.f / (float)(end - beg) : 0.f;
    float4 hsv = *(const float4*)(hs + ((size_t)node << 7) + (l32 << 2));
    float v0 = fmaxf(hsv.x + a0 * inv, 0.f);
    float v1 = fmaxf(hsv.y + a1 * inv, 0.f);
    float v2 = fmaxf(hsv.z + a2 * inv, 0.f);
    float v3 = fmaxf(hsv.w + a3 * inv, 0.f);

    float s = v0 + v1 + v2 + v3;
#pragma unroll
    for (int o = 16; o > 0; o >>= 1) s += __shfl_xor(s, o);
    float mu = s * (1.f / 128.f);
    float d0 = v0 - mu, d1 = v1 - mu, d2 = v2 - mu, d3 = v3 - mu;
    float qs = d0 * d0 + d1 * d1 + d2 * d2 + d3 * d3;
#pragma unroll
    for (int o = 16; o > 0; o >>= 1) qs += __shfl_xor(qs, o);
    float rstd = rsqrtf(qs * (1.f / 128.f) + LN_EPS);

    float4 gv = *(const float4*)(g + (l32 << 2));
    float4 bv = *(const float4*)(b + (l32 << 2));
    float o0 = d0 * rstd * gv.x + bv.x;
    float o1 = d1 * rstd * gv.y + bv.y;
    float o2 = d2 * rstd * gv.z + bv.z;
    float o3 = d3 * rstd * gv.w + bv.w;

    if (half == 0) {
        if (WF32)
            *(float4*)(h + ((size_t)node << 7) + (l32 << 2)) = make_float4(o0, o1, o2, o3);
        if (WBF16) {
            ushort4 ob = {f2bf(o0), f2bf(o1), f2bf(o2), f2bf(o3)};
            *(ushort4*)(hb + ((size_t)node << 7) + (l32 << 2)) = ob;
        }
    }
}

// ---------------- launch ----------------

extern "C" void kernel_launch(void* const* d_in, const int* in_sizes, int n_in,
                              void* d_out, int out_size, void* d_ws, size_t ws_size,
                              hipStream_t stream) {
    const float* x          = (const float*)d_in[0];
    const int*   label      = (const int*)d_in[1];
    const int*   edge_index = (const int*)d_in[2];
    const int*   edge_rel   = (const int*)d_in[3];
    const float* label_emb  = (const float*)d_in[4];
    const float* in_proj_w  = (const float*)d_in[5];
    const float* in_proj_b  = (const float*)d_in[6];
    const float* rel_emb    = (const float*)d_in[7];
    const float* lin_neigh_w = (const float*)d_in[8];
    const float* lin_self_w  = (const float*)d_in[9];
    const float* lin_self_b  = (const float*)d_in[10];
    const float* lin_rel_w   = (const float*)d_in[11];
    const float* ln_g        = (const float*)d_in[12];
    const float* ln_b        = (const float*)d_in[13];
    float* h = (float*)d_out;

    char* p = (char*)d_ws;
    auto alloc = [&](size_t bytes) {
        char* r = p;
        p += (bytes + 255) & ~(size_t)255;
        return r;
    };
    int* deg       = (int*)alloc((size_t)N_NODES * 4);
    int* offsets   = (int*)alloc((size_t)(N_NODES + 1) * 4);
    int* cursor    = (int*)alloc((size_t)N_NODES * 4);
    int* blockSums = (int*)alloc((size_t)N_SCAN_BLOCKS * 4);
    int* csr_src   = (int*)alloc((size_t)N_EDGES * 4);
    int* csr_rel   = (int*)alloc((size_t)N_EDGES * 4);
    unsigned short* hW   = (unsigned short*)alloc((size_t)N_NODES * 128 * 2);
    float*          hs   = (float*)alloc((size_t)N_NODES * 128 * 4);
    unsigned short* relW = (unsigned short*)alloc((size_t)REL_BUCKETS * 128 * 2);
    unsigned short* hb   = (unsigned short*)alloc((size_t)N_NODES * 128 * 2);
    unsigned short* Bt   = (unsigned short*)alloc((size_t)256 * 128 * 2);
    unsigned short* Btx  = (unsigned short*)alloc((size_t)128 * 160 * 2);
    unsigned short* leb  = (unsigned short*)alloc((size_t)NUM_LABELS * LABEL_DIM * 2);

    const int* src = edge_index;
    const int* dst = edge_index + N_EDGES;

    // CSR build
    hipMemsetAsync(deg, 0, (size_t)N_NODES * 4, stream);
    count_deg_kernel<<<(N_EDGES + 255) / 256, 256, 0, stream>>>(dst, deg);
    scan_tiles_kernel<<<N_SCAN_BLOCKS, SCAN_TILE, 0, stream>>>(deg, offsets, blockSums);
    scan_sums_kernel<<<1, 64, 0, stream>>>(blockSums, offsets);
    scan_add_kernel<<<N_SCAN_BLOCKS, SCAN_TILE, 0, stream>>>(offsets, blockSums, cursor);
    fill_csr_kernel<<<(N_EDGES + 255) / 256, 256, 0, stream>>>(src, dst, edge_rel, cursor,
                                                               csr_src, csr_rel);

    const int gemm_grid = (N_NODES + 63) / 64;  // 782

    // input projection: hb = relu([x | label_emb[label]] @ in_proj_w + b)  (bf16)
    f32_to_bf16_kernel<<<(N_NODES * 128 / 4) / 256, 256, 0, stream>>>(x, hb);  // hb = x_bf
    prep_in_kernel<<<(128 * 160) / 256, 256, 0, stream>>>(in_proj_w, Btx);
    prep_lemb_kernel<<<(NUM_LABELS * LABEL_DIM + 255) / 256, 256, 0, stream>>>(label_emb, leb);
    mfma_in_kernel<<<gemm_grid, 256, 0, stream>>>(hb, Btx, leb, label, in_proj_b, hb);

    for (int l = 0; l < 2; l++) {
        relw_kernel<<<(REL_BUCKETS * 128) / 256, 256, 0, stream>>>(
            rel_emb + (size_t)l * REL_BUCKETS * REL_DIM, lin_rel_w + (size_t)l * REL_DIM * 128,
            relW);
        prep_dual_kernel<<<(256 * 128) / 256, 256, 0, stream>>>(
            lin_neigh_w + (size_t)l * 128 * 128, lin_self_w + (size_t)l * 128 * 128, Bt);
        mfma_dual_kernel<<<gemm_grid, 256, 0, stream>>>(hb, Bt, lin_self_b + (size_t)l * 128,
                                                        hW, hs);
        if (l == 0) {
            agg_ln_kernel<false, true><<<(N_NODES + 3) / 4, 256, 0, stream>>>(
                hW, relW, hs, offsets, csr_src, csr_rel, ln_g, ln_b, h, hb);
        } else {
            agg_ln_kernel<true, false><<<(N_NODES + 3) / 4, 256, 0, stream>>>(
                hW, relW, hs, offsets, csr_src, csr_rel, ln_g + 128, ln_b + 128, h, hb);
        }
    }
}

// Round 5
// 377.457 us; speedup vs baseline: 2.0948x; 1.0358x over previous
//
#include <hip/hip_runtime.h>
#include <hip/hip_bf16.h>
#include <hip/hip_fp8.h>

#define N_NODES 50000
#define N_EDGES 800000
#define D 128
#define LABEL_DIM 32
#define REL_DIM 32
#define REL_BUCKETS 1024
#define NUM_LABELS 1000
#define LN_EPS 1e-5f

#define SCAN_TILE 1024
#define N_SCAN_BLOCKS ((N_NODES + SCAN_TILE - 1) / SCAN_TILE)  // 49

typedef short bf16x8 __attribute__((ext_vector_type(8)));
typedef float f32x4 __attribute__((ext_vector_type(4)));

__device__ inline unsigned short f2bf(float f) {
    __hip_bfloat16 h = __float2bfloat16(f);
    return *reinterpret_cast<unsigned short*>(&h);
}
__device__ inline float bf2f(unsigned short u) {
    return __uint_as_float((unsigned)u << 16);
}
__device__ inline unsigned char f2f8(float f) {
    __hip_fp8_e4m3 t(f);
    return (unsigned char)t.__x;
}
__device__ inline float f82f(unsigned char b) {
    __hip_fp8_e4m3 t;
    t.__x = (__hip_fp8_storage_t)b;
    return (float)t;
}

// ---------------- CSR build ----------------

__global__ __launch_bounds__(256) void count_deg_kernel(const int* __restrict__ dst,
                                                        int* __restrict__ deg) {
    int e = blockIdx.x * 256 + threadIdx.x;
    if (e < N_EDGES) atomicAdd(&deg[dst[e]], 1);
}

__global__ __launch_bounds__(SCAN_TILE) void scan_tiles_kernel(const int* __restrict__ deg,
                                                               int* __restrict__ offsets,
                                                               int* __restrict__ blockSums) {
    __shared__ int buf[SCAN_TILE];
    int i = blockIdx.x * SCAN_TILE + threadIdx.x;
    int v = (i < N_NODES) ? deg[i] : 0;
    buf[threadIdx.x] = v;
    __syncthreads();
    for (int off = 1; off < SCAN_TILE; off <<= 1) {
        int t = (threadIdx.x >= (unsigned)off) ? buf[threadIdx.x - off] : 0;
        __syncthreads();
        buf[threadIdx.x] += t;
        __syncthreads();
    }
    if (i < N_NODES) offsets[i] = buf[threadIdx.x] - v;
    if (threadIdx.x == SCAN_TILE - 1) blockSums[blockIdx.x] = buf[SCAN_TILE - 1];
}

__global__ void scan_sums_kernel(int* __restrict__ blockSums, int* __restrict__ offsets) {
    if (threadIdx.x == 0 && blockIdx.x == 0) {
        int run = 0;
        for (int i = 0; i < N_SCAN_BLOCKS; i++) {
            int v = blockSums[i];
            blockSums[i] = run;
            run += v;
        }
        offsets[N_NODES] = run;
    }
}

__global__ __launch_bounds__(SCAN_TILE) void scan_add_kernel(int* __restrict__ offsets,
                                                             const int* __restrict__ blockSums,
                                                             int* __restrict__ cursor) {
    int i = blockIdx.x * SCAN_TILE + threadIdx.x;
    if (i < N_NODES) {
        int o = offsets[i] + blockSums[blockIdx.x];
        offsets[i] = o;
        cursor[i] = o;
    }
}

// packed CSR payload: src in bits 0..15 (N<65536), rel in bits 16..25 (rel<1024)
__global__ __launch_bounds__(256) void fill_csr_kernel(const int* __restrict__ src,
                                                       const int* __restrict__ dst,
                                                       const int* __restrict__ rel,
                                                       int* __restrict__ cursor,
                                                       unsigned* __restrict__ csr_pk) {
    int e = blockIdx.x * 256 + threadIdx.x;
    if (e < N_EDGES) {
        int d = dst[e];
        int pos = atomicAdd(&cursor[d], 1);
        csr_pk[pos] = (unsigned)src[e] | ((unsigned)rel[e] << 16);
    }
}

// ---------------- weight / embedding prep ----------------

__global__ __launch_bounds__(256) void prep_dual_kernel(const float* __restrict__ Wn,
                                                        const float* __restrict__ Ws,
                                                        unsigned short* __restrict__ Bt) {
    int idx = blockIdx.x * 256 + threadIdx.x;  // 256*128 exact
    int n = idx >> 7, k = idx & 127;
    float v = (n < 128) ? Wn[k * 128 + n] : Ws[k * 128 + (n - 128)];
    Bt[idx] = f2bf(v);
}

// Btx[n][k] = in_proj_w[k][n], n<128, k<160
__global__ __launch_bounds__(256) void prep_in_kernel(const float* __restrict__ W,
                                                      unsigned short* __restrict__ Btx) {
    int idx = blockIdx.x * 256 + threadIdx.x;  // 128*160 exact
    int n = idx / 160, k = idx % 160;
    Btx[idx] = f2bf(W[k * 128 + n]);
}

__global__ __launch_bounds__(256) void prep_lemb_kernel(const float* __restrict__ le,
                                                        unsigned short* __restrict__ leb) {
    int i = blockIdx.x * 256 + threadIdx.x;
    if (i < NUM_LABELS * LABEL_DIM) leb[i] = f2bf(le[i]);
}

__global__ __launch_bounds__(256) void f32_to_bf16_kernel(const float* __restrict__ x,
                                                          unsigned short* __restrict__ xb) {
    int i = blockIdx.x * 256 + threadIdx.x;  // N*128/4 exact
    float4 v = ((const float4*)x)[i];
    ushort4 o = {f2bf(v.x), f2bf(v.y), f2bf(v.z), f2bf(v.w)};
    ((ushort4*)xb)[i] = o;
}

// ---------------- dual MFMA GEMM: [hW(fp8) | hs(bf16)+bias] = hb @ [Wn|Ws] ----
__global__ __launch_bounds__(256) void mfma_dual_kernel(const unsigned short* __restrict__ A,
                                                        const unsigned short* __restrict__ Bt,
                                                        const float* __restrict__ bias,
                                                        unsigned char* __restrict__ outF8,
                                                        unsigned short* __restrict__ outBF) {
    __shared__ unsigned short sB[256 * 128];  // 64 KiB
    const int t = threadIdx.x;
#pragma unroll
    for (int i = 0; i < 16; ++i) {
        int c = t + i * 256;
        int col = c >> 4, kch = c & 15;
        int dstc = col * 16 + (kch ^ (col & 7));
        *(bf16x8*)&sB[dstc * 8] = *(const bf16x8*)&Bt[c * 8];
    }
    __syncthreads();

    const int wave = t >> 6, lane = t & 63;
    const int m16 = lane & 15, q = lane >> 4;
    const int r0 = blockIdx.x * 64 + wave * 16;
    const int arow = r0 + m16;
    const bool avalid = arow < N_NODES;
    const unsigned short* ap = A + (size_t)(avalid ? arow : 0) * 128 + q * 8;

    f32x4 acc[16];
#pragma unroll
    for (int ct = 0; ct < 16; ++ct) acc[ct] = (f32x4){0.f, 0.f, 0.f, 0.f};

#pragma unroll
    for (int ki = 0; ki < 4; ++ki) {
        bf16x8 af = *(const bf16x8*)(ap + ki * 32);
        if (!avalid) af = (bf16x8){0, 0, 0, 0, 0, 0, 0, 0};
        int kch = ki * 4 + q;
#pragma unroll
        for (int ct = 0; ct < 16; ++ct) {
            int col = ct * 16 + m16;
            int chunk = col * 16 + (kch ^ (m16 & 7));
            bf16x8 bf = *(const bf16x8*)&sB[chunk * 8];
            acc[ct] = __builtin_amdgcn_mfma_f32_16x16x32_bf16(af, bf, acc[ct], 0, 0, 0);
        }
    }

#pragma unroll
    for (int ct = 0; ct < 16; ++ct) {
        int colg = ct * 16 + m16;
#pragma unroll
        for (int r = 0; r < 4; ++r) {
            int row = r0 + q * 4 + r;
            if (row < N_NODES) {
                float v = acc[ct][r];
                if (ct < 8)
                    outF8[(size_t)row * 128 + colg] = f2f8(v);
                else
                    outBF[(size_t)row * 128 + (colg - 128)] = f2bf(v + bias[colg - 128]);
            }
        }
    }
}

// ---------------- input-proj MFMA GEMM (K=160, fused label emb + bias + relu) ----
__global__ __launch_bounds__(256) void mfma_in_kernel(const unsigned short* __restrict__ A,
                                                      const unsigned short* __restrict__ Btx,
                                                      const unsigned short* __restrict__ leb,
                                                      const int* __restrict__ label,
                                                      const float* __restrict__ bias,
                                                      unsigned short* __restrict__ outBF) {
    __shared__ unsigned short sB[128 * 160];  // 40 KiB; [col][20 chunks of 8]
    const int t = threadIdx.x;
#pragma unroll
    for (int i = 0; i < 10; ++i) {
        int c = t + i * 256;
        int col = c / 20, kch = c % 20;
        int dstc = col * 20 + (kch < 16 ? (kch ^ (col & 7)) : kch);
        *(bf16x8*)&sB[dstc * 8] = *(const bf16x8*)&Btx[c * 8];
    }
    __syncthreads();

    const int wave = t >> 6, lane = t & 63;
    const int m16 = lane & 15, q = lane >> 4;
    const int r0 = blockIdx.x * 64 + wave * 16;
    const int arow = r0 + m16;
    const bool avalid = arow < N_NODES;
    const unsigned short* ap = A + (size_t)(avalid ? arow : 0) * 128 + q * 8;

    f32x4 acc[8];
#pragma unroll
    for (int ct = 0; ct < 8; ++ct) acc[ct] = (f32x4){0.f, 0.f, 0.f, 0.f};

#pragma unroll
    for (int ki = 0; ki < 4; ++ki) {
        bf16x8 af = *(const bf16x8*)(ap + ki * 32);
        if (!avalid) af = (bf16x8){0, 0, 0, 0, 0, 0, 0, 0};
        int kch = ki * 4 + q;
#pragma unroll
        for (int ct = 0; ct < 8; ++ct) {
            int col = ct * 16 + m16;
            int chunk = col * 20 + (kch ^ (m16 & 7));
            bf16x8 bf = *(const bf16x8*)&sB[chunk * 8];
            acc[ct] = __builtin_amdgcn_mfma_f32_16x16x32_bf16(af, bf, acc[ct], 0, 0, 0);
        }
    }
    {   // label-embedding K-chunk (k = 128..159)
        int lb = avalid ? label[arow] : 0;
        bf16x8 af = *(const bf16x8*)(leb + (size_t)lb * LABEL_DIM + q * 8);
        if (!avalid) af = (bf16x8){0, 0, 0, 0, 0, 0, 0, 0};
        int kch = 16 + q;
#pragma unroll
        for (int ct = 0; ct < 8; ++ct) {
            int col = ct * 16 + m16;
            int chunk = col * 20 + kch;
            bf16x8 bf = *(const bf16x8*)&sB[chunk * 8];
            acc[ct] = __builtin_amdgcn_mfma_f32_16x16x32_bf16(af, bf, acc[ct], 0, 0, 0);
        }
    }

#pragma unroll
    for (int ct = 0; ct < 8; ++ct) {
        int colg = ct * 16 + m16;
#pragma unroll
        for (int r = 0; r < 4; ++r) {
            int row = r0 + q * 4 + r;
            if (row < N_NODES) {
                float v = fmaxf(acc[ct][r] + bias[colg], 0.f);
                outBF[(size_t)row * 128 + colg] = f2bf(v);
            }
        }
    }
}

// ---------------- relW[1024,128] (bf16) = rel_emb[l] @ lin_rel_w[l] ----------------
__global__ __launch_bounds__(256) void relw_kernel(const float* __restrict__ rel_emb,
                                                   const float* __restrict__ Wr,
                                                   unsigned short* __restrict__ relW) {
    __shared__ float sw[REL_DIM * 128];
    for (int i = threadIdx.x; i < REL_DIM * 128; i += 256) sw[i] = Wr[i];
    __syncthreads();
    int idx = blockIdx.x * 256 + threadIdx.x;  // 1024*128 exact
    int r = idx >> 7, c = idx & 127;
    const float* re = rel_emb + (size_t)r * REL_DIM;
    float a = 0.f;
#pragma unroll
    for (int k = 0; k < REL_DIM; k++) a = fmaf(re[k], sw[k * 128 + c], a);
    relW[idx] = f2bf(a);
}

// ---------------- edge gather + mean + self + relu + layernorm ----------------
// One wave per node; lanes 0-31 even edges, 32-63 odd edges. hW rows are fp8
// (uchar4/lane = 4 cols, 128B/row), relW bf16 (ushort4), hs bf16, index packed.
template <bool WF32, bool WBF16>
__global__ __launch_bounds__(256) void agg_ln_kernel(const unsigned char* __restrict__ hW8,
                                                     const unsigned short* __restrict__ relW,
                                                     const unsigned short* __restrict__ hsb,
                                                     const int* __restrict__ offsets,
                                                     const unsigned* __restrict__ csr_pk,
                                                     const float* __restrict__ g,
                                                     const float* __restrict__ b,
                                                     float* __restrict__ h,
                                                     unsigned short* __restrict__ hb) {
    const int wave = threadIdx.x >> 6;
    const int lane = threadIdx.x & 63;
    const int node = blockIdx.x * 4 + wave;
    if (node >= N_NODES) return;
    const int half = lane >> 5, l32 = lane & 31;
    const int beg = offsets[node], end = offsets[node + 1];

    float a0 = 0.f, a1 = 0.f, a2 = 0.f, a3 = 0.f;
    int e = beg;
    for (; e + 1 < end; e += 2) {
        unsigned pk = csr_pk[e + half];
        unsigned s = pk & 0xffffu;
        unsigned r = pk >> 16;
        uchar4 hv = *(const uchar4*)(hW8 + ((size_t)s << 7) + (l32 << 2));
        ushort4 rv = *(const ushort4*)(relW + ((size_t)r << 7) + (l32 << 2));
        a0 += f82f(hv.x) + bf2f(rv.x);
        a1 += f82f(hv.y) + bf2f(rv.y);
        a2 += f82f(hv.z) + bf2f(rv.z);
        a3 += f82f(hv.w) + bf2f(rv.w);
    }
    if (e < end && half == 0) {
        unsigned pk = csr_pk[e];
        unsigned s = pk & 0xffffu;
        unsigned r = pk >> 16;
        uchar4 hv = *(const uchar4*)(hW8 + ((size_t)s << 7) + (l32 << 2));
        ushort4 rv = *(const ushort4*)(relW + ((size_t)r << 7) + (l32 << 2));
        a0 += f82f(hv.x) + bf2f(rv.x);
        a1 += f82f(hv.y) + bf2f(rv.y);
        a2 += f82f(hv.z) + bf2f(rv.z);
        a3 += f82f(hv.w) + bf2f(rv.w);
    }
    a0 += __shfl_xor(a0, 32);
    a1 += __shfl_xor(a1, 32);
    a2 += __shfl_xor(a2, 32);
    a3 += __shfl_xor(a3, 32);

    float inv = (end > beg) ? 1.f / (float)(end - beg) : 0.f;
    ushort4 hsv = *(const ushort4*)(hsb + ((size_t)node << 7) + (l32 << 2));
    float v0 = fmaxf(bf2f(hsv.x) + a0 * inv, 0.f);
    float v1 = fmaxf(bf2f(hsv.y) + a1 * inv, 0.f);
    float v2 = fmaxf(bf2f(hsv.z) + a2 * inv, 0.f);
    float v3 = fmaxf(bf2f(hsv.w) + a3 * inv, 0.f);

    float s = v0 + v1 + v2 + v3;
#pragma unroll
    for (int o = 16; o > 0; o >>= 1) s += __shfl_xor(s, o);
    float mu = s * (1.f / 128.f);
    float d0 = v0 - mu, d1 = v1 - mu, d2 = v2 - mu, d3 = v3 - mu;
    float qs = d0 * d0 + d1 * d1 + d2 * d2 + d3 * d3;
#pragma unroll
    for (int o = 16; o > 0; o >>= 1) qs += __shfl_xor(qs, o);
    float rstd = rsqrtf(qs * (1.f / 128.f) + LN_EPS);

    float4 gv = *(const float4*)(g + (l32 << 2));
    float4 bv = *(const float4*)(b + (l32 << 2));
    float o0 = d0 * rstd * gv.x + bv.x;
    float o1 = d1 * rstd * gv.y + bv.y;
    float o2 = d2 * rstd * gv.z + bv.z;
    float o3 = d3 * rstd * gv.w + bv.w;

    if (half == 0) {
        if (WF32)
            *(float4*)(h + ((size_t)node << 7) + (l32 << 2)) = make_float4(o0, o1, o2, o3);
        if (WBF16) {
            ushort4 ob = {f2bf(o0), f2bf(o1), f2bf(o2), f2bf(o3)};
            *(ushort4*)(hb + ((size_t)node << 7) + (l32 << 2)) = ob;
        }
    }
}

// ---------------- launch ----------------

extern "C" void kernel_launch(void* const* d_in, const int* in_sizes, int n_in,
                              void* d_out, int out_size, void* d_ws, size_t ws_size,
                              hipStream_t stream) {
    const float* x          = (const float*)d_in[0];
    const int*   label      = (const int*)d_in[1];
    const int*   edge_index = (const int*)d_in[2];
    const int*   edge_rel   = (const int*)d_in[3];
    const float* label_emb  = (const float*)d_in[4];
    const float* in_proj_w  = (const float*)d_in[5];
    const float* in_proj_b  = (const float*)d_in[6];
    const float* rel_emb    = (const float*)d_in[7];
    const float* lin_neigh_w = (const float*)d_in[8];
    const float* lin_self_w  = (const float*)d_in[9];
    const float* lin_self_b  = (const float*)d_in[10];
    const float* lin_rel_w   = (const float*)d_in[11];
    const float* ln_g        = (const float*)d_in[12];
    const float* ln_b        = (const float*)d_in[13];
    float* h = (float*)d_out;

    char* p = (char*)d_ws;
    auto alloc = [&](size_t bytes) {
        char* r = p;
        p += (bytes + 255) & ~(size_t)255;
        return r;
    };
    int* deg       = (int*)alloc((size_t)N_NODES * 4);
    int* offsets   = (int*)alloc((size_t)(N_NODES + 1) * 4);
    int* cursor    = (int*)alloc((size_t)N_NODES * 4);
    int* blockSums = (int*)alloc((size_t)N_SCAN_BLOCKS * 4);
    unsigned* csr_pk = (unsigned*)alloc((size_t)N_EDGES * 4);
    unsigned char*  hW8  = (unsigned char*)alloc((size_t)N_NODES * 128);
    unsigned short* hsb  = (unsigned short*)alloc((size_t)N_NODES * 128 * 2);
    unsigned short* relW = (unsigned short*)alloc((size_t)REL_BUCKETS * 128 * 2);
    unsigned short* hb   = (unsigned short*)alloc((size_t)N_NODES * 128 * 2);
    unsigned short* Bt   = (unsigned short*)alloc((size_t)256 * 128 * 2);
    unsigned short* Btx  = (unsigned short*)alloc((size_t)128 * 160 * 2);
    unsigned short* leb  = (unsigned short*)alloc((size_t)NUM_LABELS * LABEL_DIM * 2);

    const int* src = edge_index;
    const int* dst = edge_index + N_EDGES;

    // CSR build
    hipMemsetAsync(deg, 0, (size_t)N_NODES * 4, stream);
    count_deg_kernel<<<(N_EDGES + 255) / 256, 256, 0, stream>>>(dst, deg);
    scan_tiles_kernel<<<N_SCAN_BLOCKS, SCAN_TILE, 0, stream>>>(deg, offsets, blockSums);
    scan_sums_kernel<<<1, 64, 0, stream>>>(blockSums, offsets);
    scan_add_kernel<<<N_SCAN_BLOCKS, SCAN_TILE, 0, stream>>>(offsets, blockSums, cursor);
    fill_csr_kernel<<<(N_EDGES + 255) / 256, 256, 0, stream>>>(src, dst, edge_rel, cursor,
                                                               csr_pk);

    const int gemm_grid = (N_NODES + 63) / 64;  // 782

    // input projection: hb = relu([x | label_emb[label]] @ in_proj_w + b)  (bf16)
    f32_to_bf16_kernel<<<(N_NODES * 128 / 4) / 256, 256, 0, stream>>>(x, hb);  // hb = x_bf
    prep_in_kernel<<<(128 * 160) / 256, 256, 0, stream>>>(in_proj_w, Btx);
    prep_lemb_kernel<<<(NUM_LABELS * LABEL_DIM + 255) / 256, 256, 0, stream>>>(label_emb, leb);
    mfma_in_kernel<<<gemm_grid, 256, 0, stream>>>(hb, Btx, leb, label, in_proj_b, hb);

    for (int l = 0; l < 2; l++) {
        relw_kernel<<<(REL_BUCKETS * 128) / 256, 256, 0, stream>>>(
            rel_emb + (size_t)l * REL_BUCKETS * REL_DIM, lin_rel_w + (size_t)l * REL_DIM * 128,
            relW);
        prep_dual_kernel<<<(256 * 128) / 256, 256, 0, stream>>>(
            lin_neigh_w + (size_t)l * 128 * 128, lin_self_w + (size_t)l * 128 * 128, Bt);
        mfma_dual_kernel<<<gemm_grid, 256, 0, stream>>>(hb, Bt, lin_self_b + (size_t)l * 128,
                                                        hW8, hsb);
        if (l == 0) {
            agg_ln_kernel<false, true><<<(N_NODES + 3) / 4, 256, 0, stream>>>(
                hW8, relW, hsb, offsets, csr_pk, ln_g, ln_b, h, hb);
        } else {
            agg_ln_kernel<true, false><<<(N_NODES + 3) / 4, 256, 0, stream>>>(
                hW8, relW, hsb, offsets, csr_pk, ln_g + 128, ln_b + 128, h, hb);
        }
    }
}

// Round 6
// 349.227 us; speedup vs baseline: 2.2641x; 1.0808x over previous
//
#include <hip/hip_runtime.h>
#include <hip/hip_bf16.h>

#define N_NODES 50000
#define N_EDGES 800000
#define D 128
#define LABEL_DIM 32
#define REL_DIM 32
#define REL_BUCKETS 1024
#define NUM_LABELS 1000
#define LN_EPS 1e-5f

#define SCAN_TILE 1024
#define N_SCAN_BLOCKS ((N_NODES + SCAN_TILE - 1) / SCAN_TILE)  // 49

typedef short bf16x8 __attribute__((ext_vector_type(8)));
typedef float f32x4 __attribute__((ext_vector_type(4)));

__device__ inline unsigned short f2bf(float f) {
    __hip_bfloat16 h = __float2bfloat16(f);
    return *reinterpret_cast<unsigned short*>(&h);
}
__device__ inline float bf2f(unsigned short u) {
    return __uint_as_float((unsigned)u << 16);
}

// ---------------- CSR build ----------------

__global__ __launch_bounds__(256) void count_deg_kernel(const int* __restrict__ dst,
                                                        int* __restrict__ deg) {
    int e = blockIdx.x * 256 + threadIdx.x;
    if (e < N_EDGES) atomicAdd(&deg[dst[e]], 1);
}

__global__ __launch_bounds__(SCAN_TILE) void scan_tiles_kernel(const int* __restrict__ deg,
                                                               int* __restrict__ offsets,
                                                               int* __restrict__ blockSums) {
    __shared__ int buf[SCAN_TILE];
    int i = blockIdx.x * SCAN_TILE + threadIdx.x;
    int v = (i < N_NODES) ? deg[i] : 0;
    buf[threadIdx.x] = v;
    __syncthreads();
    for (int off = 1; off < SCAN_TILE; off <<= 1) {
        int t = (threadIdx.x >= (unsigned)off) ? buf[threadIdx.x - off] : 0;
        __syncthreads();
        buf[threadIdx.x] += t;
        __syncthreads();
    }
    if (i < N_NODES) offsets[i] = buf[threadIdx.x] - v;
    if (threadIdx.x == SCAN_TILE - 1) blockSums[blockIdx.x] = buf[SCAN_TILE - 1];
}

__global__ void scan_sums_kernel(int* __restrict__ blockSums, int* __restrict__ offsets) {
    if (threadIdx.x == 0 && blockIdx.x == 0) {
        int run = 0;
        for (int i = 0; i < N_SCAN_BLOCKS; i++) {
            int v = blockSums[i];
            blockSums[i] = run;
            run += v;
        }
        offsets[N_NODES] = run;
    }
}

__global__ __launch_bounds__(SCAN_TILE) void scan_add_kernel(int* __restrict__ offsets,
                                                             const int* __restrict__ blockSums,
                                                             int* __restrict__ cursor) {
    int i = blockIdx.x * SCAN_TILE + threadIdx.x;
    if (i < N_NODES) {
        int o = offsets[i] + blockSums[blockIdx.x];
        offsets[i] = o;
        cursor[i] = o;
    }
}

// packed CSR payload: src in bits 0..15 (N<65536), rel in bits 16..25 (rel<1024)
__global__ __launch_bounds__(256) void fill_csr_kernel(const int* __restrict__ src,
                                                       const int* __restrict__ dst,
                                                       const int* __restrict__ rel,
                                                       int* __restrict__ cursor,
                                                       unsigned* __restrict__ csr_pk) {
    int e = blockIdx.x * 256 + threadIdx.x;
    if (e < N_EDGES) {
        int d = dst[e];
        int pos = atomicAdd(&cursor[d], 1);
        csr_pk[pos] = (unsigned)src[e] | ((unsigned)rel[e] << 16);
    }
}

// ---------------- weight / embedding prep ----------------

__global__ __launch_bounds__(256) void prep_dual_kernel(const float* __restrict__ Wn,
                                                        const float* __restrict__ Ws,
                                                        unsigned short* __restrict__ Bt) {
    int idx = blockIdx.x * 256 + threadIdx.x;  // 256*128 exact
    int n = idx >> 7, k = idx & 127;
    float v = (n < 128) ? Wn[k * 128 + n] : Ws[k * 128 + (n - 128)];
    Bt[idx] = f2bf(v);
}

// Btx[n][k] = in_proj_w[k][n], n<128, k<160
__global__ __launch_bounds__(256) void prep_in_kernel(const float* __restrict__ W,
                                                      unsigned short* __restrict__ Btx) {
    int idx = blockIdx.x * 256 + threadIdx.x;  // 128*160 exact
    int n = idx / 160, k = idx % 160;
    Btx[idx] = f2bf(W[k * 128 + n]);
}

__global__ __launch_bounds__(256) void prep_lemb_kernel(const float* __restrict__ le,
                                                        unsigned short* __restrict__ leb) {
    int i = blockIdx.x * 256 + threadIdx.x;
    if (i < NUM_LABELS * LABEL_DIM) leb[i] = f2bf(le[i]);
}

// ---------------- per-half MFMA GEMM: 128 cols, 32 KiB B-tile -----------------
// blockIdx.y==0: outHW (bf16, neigh weights). blockIdx.y==1: outHS (bf16, +bias).
__global__ __launch_bounds__(256) void mfma_half_kernel(const unsigned short* __restrict__ A,
                                                        const unsigned short* __restrict__ Bt,
                                                        const float* __restrict__ bias,
                                                        unsigned short* __restrict__ outHW,
                                                        unsigned short* __restrict__ outHS) {
    __shared__ unsigned short sB[128 * 128];  // 32 KiB
    const int t = threadIdx.x;
    const unsigned short* Bsrc = Bt + (size_t)blockIdx.y * 128 * 128;
#pragma unroll
    for (int i = 0; i < 8; ++i) {
        int c = t + i * 256;  // 2048 chunks
        int col = c >> 4, kch = c & 15;
        int dstc = col * 16 + (kch ^ (col & 7));
        *(bf16x8*)&sB[dstc * 8] = *(const bf16x8*)&Bsrc[c * 8];
    }
    __syncthreads();

    const int wave = t >> 6, lane = t & 63;
    const int m16 = lane & 15, q = lane >> 4;
    const int r0 = blockIdx.x * 64 + wave * 16;
    const int arow = r0 + m16;
    const bool avalid = arow < N_NODES;
    const unsigned short* ap = A + (size_t)(avalid ? arow : 0) * 128 + q * 8;

    f32x4 acc[8];
#pragma unroll
    for (int ct = 0; ct < 8; ++ct) acc[ct] = (f32x4){0.f, 0.f, 0.f, 0.f};

#pragma unroll
    for (int ki = 0; ki < 4; ++ki) {
        bf16x8 af = *(const bf16x8*)(ap + ki * 32);
        if (!avalid) af = (bf16x8){0, 0, 0, 0, 0, 0, 0, 0};
        int kch = ki * 4 + q;
#pragma unroll
        for (int ct = 0; ct < 8; ++ct) {
            int col = ct * 16 + m16;
            int chunk = col * 16 + (kch ^ (m16 & 7));
            bf16x8 bf = *(const bf16x8*)&sB[chunk * 8];
            acc[ct] = __builtin_amdgcn_mfma_f32_16x16x32_bf16(af, bf, acc[ct], 0, 0, 0);
        }
    }

    if (blockIdx.y == 0) {
#pragma unroll
        for (int ct = 0; ct < 8; ++ct) {
            int colg = ct * 16 + m16;
#pragma unroll
            for (int r = 0; r < 4; ++r) {
                int row = r0 + q * 4 + r;
                if (row < N_NODES) outHW[(size_t)row * 128 + colg] = f2bf(acc[ct][r]);
            }
        }
    } else {
#pragma unroll
        for (int ct = 0; ct < 8; ++ct) {
            int colg = ct * 16 + m16;
            float bs = bias[colg];
#pragma unroll
            for (int r = 0; r < 4; ++r) {
                int row = r0 + q * 4 + r;
                if (row < N_NODES) outHS[(size_t)row * 128 + colg] = f2bf(acc[ct][r] + bs);
            }
        }
    }
}

// ---------------- input-proj MFMA GEMM (fp32 A, K=160, fused lemb+bias+relu) ----
__global__ __launch_bounds__(256) void mfma_in_kernel(const float* __restrict__ X,
                                                      const unsigned short* __restrict__ Btx,
                                                      const unsigned short* __restrict__ leb,
                                                      const int* __restrict__ label,
                                                      const float* __restrict__ bias,
                                                      unsigned short* __restrict__ outBF) {
    __shared__ unsigned short sB[128 * 160];  // 40 KiB; [col][20 chunks of 8]
    const int t = threadIdx.x;
#pragma unroll
    for (int i = 0; i < 10; ++i) {
        int c = t + i * 256;
        int col = c / 20, kch = c % 20;
        int dstc = col * 20 + (kch < 16 ? (kch ^ (col & 7)) : kch);
        *(bf16x8*)&sB[dstc * 8] = *(const bf16x8*)&Btx[c * 8];
    }
    __syncthreads();

    const int wave = t >> 6, lane = t & 63;
    const int m16 = lane & 15, q = lane >> 4;
    const int r0 = blockIdx.x * 64 + wave * 16;
    const int arow = r0 + m16;
    const bool avalid = arow < N_NODES;
    const float* xp = X + (size_t)(avalid ? arow : 0) * 128 + q * 8;

    f32x4 acc[8];
#pragma unroll
    for (int ct = 0; ct < 8; ++ct) acc[ct] = (f32x4){0.f, 0.f, 0.f, 0.f};

#pragma unroll
    for (int ki = 0; ki < 4; ++ki) {
        bf16x8 af;
        if (avalid) {
            float4 v0 = *(const float4*)(xp + ki * 32);
            float4 v1 = *(const float4*)(xp + ki * 32 + 4);
            af[0] = (short)f2bf(v0.x); af[1] = (short)f2bf(v0.y);
            af[2] = (short)f2bf(v0.z); af[3] = (short)f2bf(v0.w);
            af[4] = (short)f2bf(v1.x); af[5] = (short)f2bf(v1.y);
            af[6] = (short)f2bf(v1.z); af[7] = (short)f2bf(v1.w);
        } else {
            af = (bf16x8){0, 0, 0, 0, 0, 0, 0, 0};
        }
        int kch = ki * 4 + q;
#pragma unroll
        for (int ct = 0; ct < 8; ++ct) {
            int col = ct * 16 + m16;
            int chunk = col * 20 + (kch ^ (m16 & 7));
            bf16x8 bf = *(const bf16x8*)&sB[chunk * 8];
            acc[ct] = __builtin_amdgcn_mfma_f32_16x16x32_bf16(af, bf, acc[ct], 0, 0, 0);
        }
    }
    {   // label-embedding K-chunk (k = 128..159)
        int lb = avalid ? label[arow] : 0;
        bf16x8 af = *(const bf16x8*)(leb + (size_t)lb * LABEL_DIM + q * 8);
        if (!avalid) af = (bf16x8){0, 0, 0, 0, 0, 0, 0, 0};
        int kch = 16 + q;
#pragma unroll
        for (int ct = 0; ct < 8; ++ct) {
            int col = ct * 16 + m16;
            int chunk = col * 20 + kch;
            bf16x8 bf = *(const bf16x8*)&sB[chunk * 8];
            acc[ct] = __builtin_amdgcn_mfma_f32_16x16x32_bf16(af, bf, acc[ct], 0, 0, 0);
        }
    }

#pragma unroll
    for (int ct = 0; ct < 8; ++ct) {
        int colg = ct * 16 + m16;
        float bs = bias[colg];
#pragma unroll
        for (int r = 0; r < 4; ++r) {
            int row = r0 + q * 4 + r;
            if (row < N_NODES) {
                float v = fmaxf(acc[ct][r] + bs, 0.f);
                outBF[(size_t)row * 128 + colg] = f2bf(v);
            }
        }
    }
}

// ---------------- relW[1024,128] (bf16) = rel_emb[l] @ lin_rel_w[l] ----------------
__global__ __launch_bounds__(256) void relw_kernel(const float* __restrict__ rel_emb,
                                                   const float* __restrict__ Wr,
                                                   unsigned short* __restrict__ relW) {
    __shared__ float sw[REL_DIM * 128];
    for (int i = threadIdx.x; i < REL_DIM * 128; i += 256) sw[i] = Wr[i];
    __syncthreads();
    int idx = blockIdx.x * 256 + threadIdx.x;  // 1024*128 exact
    int r = idx >> 7, c = idx & 127;
    const float* re = rel_emb + (size_t)r * REL_DIM;
    float a = 0.f;
#pragma unroll
    for (int k = 0; k < REL_DIM; k++) a = fmaf(re[k], sw[k * 128 + c], a);
    relW[idx] = f2bf(a);
}

// ---------------- edge gather + mean + self + relu + layernorm ----------------
// One wave per node. Quarter q (16 lanes) handles edge e+q; lane covers 8 cols
// at l16*8 via one 16B bf16x8 load per table. Cross-quarter shfl reduce; LN
// over 16 lanes (values replicated across quarters). Tail edges masked by fma.
template <bool WF32, bool WBF16>
__global__ __launch_bounds__(256) void agg_ln_kernel(const unsigned short* __restrict__ hW,
                                                     const unsigned short* __restrict__ relW,
                                                     const unsigned short* __restrict__ hsb,
                                                     const int* __restrict__ offsets,
                                                     const unsigned* __restrict__ csr_pk,
                                                     const float* __restrict__ g,
                                                     const float* __restrict__ b,
                                                     float* __restrict__ h,
                                                     unsigned short* __restrict__ hb) {
    const int wave = threadIdx.x >> 6;
    const int lane = threadIdx.x & 63;
    const int node = blockIdx.x * 4 + wave;
    if (node >= N_NODES) return;
    const int q = lane >> 4, l16 = lane & 15;
    const int beg = offsets[node], end = offsets[node + 1];
    const int co = l16 * 8;  // column base for this lane

    float acc[8];
#pragma unroll
    for (int j = 0; j < 8; ++j) acc[j] = 0.f;

    for (int e = beg; e < end; e += 4) {
        int idx = e + q;
        float m = 1.f;
        if (idx >= end) { idx = e; m = 0.f; }  // replay quarter-0 edge, masked
        unsigned pk = csr_pk[idx];
        unsigned s = pk & 0xffffu;
        unsigned r = pk >> 16;
        bf16x8 hv = *(const bf16x8*)(hW + ((size_t)s << 7) + co);
        bf16x8 rv = *(const bf16x8*)(relW + ((size_t)r << 7) + co);
#pragma unroll
        for (int j = 0; j < 8; ++j) {
            float val = bf2f((unsigned short)hv[j]) + bf2f((unsigned short)rv[j]);
            acc[j] = fmaf(m, val, acc[j]);
        }
    }
    // combine quarters: after this every lane holds full sums for its 8 cols
#pragma unroll
    for (int j = 0; j < 8; ++j) {
        acc[j] += __shfl_xor(acc[j], 16);
        acc[j] += __shfl_xor(acc[j], 32);
    }

    float inv = (end > beg) ? 1.f / (float)(end - beg) : 0.f;
    bf16x8 hsv = *(const bf16x8*)(hsb + ((size_t)node << 7) + co);
    float v[8];
    float s_sum = 0.f;
#pragma unroll
    for (int j = 0; j < 8; ++j) {
        v[j] = fmaxf(bf2f((unsigned short)hsv[j]) + acc[j] * inv, 0.f);
        s_sum += v[j];
    }
#pragma unroll
    for (int o = 8; o > 0; o >>= 1) s_sum += __shfl_xor(s_sum, o);
    float mu = s_sum * (1.f / 128.f);
    float qs = 0.f;
    float d[8];
#pragma unroll
    for (int j = 0; j < 8; ++j) {
        d[j] = v[j] - mu;
        qs += d[j] * d[j];
    }
#pragma unroll
    for (int o = 8; o > 0; o >>= 1) qs += __shfl_xor(qs, o);
    float rstd = rsqrtf(qs * (1.f / 128.f) + LN_EPS);

    if (q == 0) {
        float4 g0 = *(const float4*)(g + co), g1 = *(const float4*)(g + co + 4);
        float4 b0 = *(const float4*)(b + co), b1 = *(const float4*)(b + co + 4);
        float o0 = d[0] * rstd * g0.x + b0.x;
        float o1 = d[1] * rstd * g0.y + b0.y;
        float o2 = d[2] * rstd * g0.z + b0.z;
        float o3 = d[3] * rstd * g0.w + b0.w;
        float o4 = d[4] * rstd * g1.x + b1.x;
        float o5 = d[5] * rstd * g1.y + b1.y;
        float o6 = d[6] * rstd * g1.z + b1.z;
        float o7 = d[7] * rstd * g1.w + b1.w;
        if (WF32) {
            *(float4*)(h + ((size_t)node << 7) + co) = make_float4(o0, o1, o2, o3);
            *(float4*)(h + ((size_t)node << 7) + co + 4) = make_float4(o4, o5, o6, o7);
        }
        if (WBF16) {
            bf16x8 ob;
            ob[0] = (short)f2bf(o0); ob[1] = (short)f2bf(o1);
            ob[2] = (short)f2bf(o2); ob[3] = (short)f2bf(o3);
            ob[4] = (short)f2bf(o4); ob[5] = (short)f2bf(o5);
            ob[6] = (short)f2bf(o6); ob[7] = (short)f2bf(o7);
            *(bf16x8*)(hb + ((size_t)node << 7) + co) = ob;
        }
    }
}

// ---------------- launch ----------------

extern "C" void kernel_launch(void* const* d_in, const int* in_sizes, int n_in,
                              void* d_out, int out_size, void* d_ws, size_t ws_size,
                              hipStream_t stream) {
    const float* x          = (const float*)d_in[0];
    const int*   label      = (const int*)d_in[1];
    const int*   edge_index = (const int*)d_in[2];
    const int*   edge_rel   = (const int*)d_in[3];
    const float* label_emb  = (const float*)d_in[4];
    const float* in_proj_w  = (const float*)d_in[5];
    const float* in_proj_b  = (const float*)d_in[6];
    const float* rel_emb    = (const float*)d_in[7];
    const float* lin_neigh_w = (const float*)d_in[8];
    const float* lin_self_w  = (const float*)d_in[9];
    const float* lin_self_b  = (const float*)d_in[10];
    const float* lin_rel_w   = (const float*)d_in[11];
    const float* ln_g        = (const float*)d_in[12];
    const float* ln_b        = (const float*)d_in[13];
    float* h = (float*)d_out;

    char* p = (char*)d_ws;
    auto alloc = [&](size_t bytes) {
        char* r = p;
        p += (bytes + 255) & ~(size_t)255;
        return r;
    };
    int* deg       = (int*)alloc((size_t)N_NODES * 4);
    int* offsets   = (int*)alloc((size_t)(N_NODES + 1) * 4);
    int* cursor    = (int*)alloc((size_t)N_NODES * 4);
    int* blockSums = (int*)alloc((size_t)N_SCAN_BLOCKS * 4);
    unsigned* csr_pk = (unsigned*)alloc((size_t)N_EDGES * 4);
    unsigned short* hW   = (unsigned short*)alloc((size_t)N_NODES * 128 * 2);
    unsigned short* hsb  = (unsigned short*)alloc((size_t)N_NODES * 128 * 2);
    unsigned short* relW = (unsigned short*)alloc((size_t)REL_BUCKETS * 128 * 2);
    unsigned short* hb   = (unsigned short*)alloc((size_t)N_NODES * 128 * 2);
    unsigned short* Bt   = (unsigned short*)alloc((size_t)256 * 128 * 2);
    unsigned short* Btx  = (unsigned short*)alloc((size_t)128 * 160 * 2);
    unsigned short* leb  = (unsigned short*)alloc((size_t)NUM_LABELS * LABEL_DIM * 2);

    const int* src = edge_index;
    const int* dst = edge_index + N_EDGES;

    // CSR build
    hipMemsetAsync(deg, 0, (size_t)N_NODES * 4, stream);
    count_deg_kernel<<<(N_EDGES + 255) / 256, 256, 0, stream>>>(dst, deg);
    scan_tiles_kernel<<<N_SCAN_BLOCKS, SCAN_TILE, 0, stream>>>(deg, offsets, blockSums);
    scan_sums_kernel<<<1, 64, 0, stream>>>(blockSums, offsets);
    scan_add_kernel<<<N_SCAN_BLOCKS, SCAN_TILE, 0, stream>>>(offsets, blockSums, cursor);
    fill_csr_kernel<<<(N_EDGES + 255) / 256, 256, 0, stream>>>(src, dst, edge_rel, cursor,
                                                               csr_pk);

    const int gemm_grid = (N_NODES + 63) / 64;  // 782

    // input projection: hb = relu([x | label_emb[label]] @ in_proj_w + b)  (bf16)
    prep_in_kernel<<<(128 * 160) / 256, 256, 0, stream>>>(in_proj_w, Btx);
    prep_lemb_kernel<<<(NUM_LABELS * LABEL_DIM + 255) / 256, 256, 0, stream>>>(label_emb, leb);
    mfma_in_kernel<<<gemm_grid, 256, 0, stream>>>(x, Btx, leb, label, in_proj_b, hb);

    for (int l = 0; l < 2; l++) {
        relw_kernel<<<(REL_BUCKETS * 128) / 256, 256, 0, stream>>>(
            rel_emb + (size_t)l * REL_BUCKETS * REL_DIM, lin_rel_w + (size_t)l * REL_DIM * 128,
            relW);
        prep_dual_kernel<<<(256 * 128) / 256, 256, 0, stream>>>(
            lin_neigh_w + (size_t)l * 128 * 128, lin_self_w + (size_t)l * 128 * 128, Bt);
        mfma_half_kernel<<<dim3(gemm_grid, 2), 256, 0, stream>>>(
            hb, Bt, lin_self_b + (size_t)l * 128, hW, hsb);
        if (l == 0) {
            agg_ln_kernel<false, true><<<(N_NODES + 3) / 4, 256, 0, stream>>>(
                hW, relW, hsb, offsets, csr_pk, ln_g, ln_b, h, hb);
        } else {
            agg_ln_kernel<true, false><<<(N_NODES + 3) / 4, 256, 0, stream>>>(
                hW, relW, hsb, offsets, csr_pk, ln_g + 128, ln_b + 128, h, hb);
        }
    }
}

// Round 7
// 333.724 us; speedup vs baseline: 2.3693x; 1.0465x over previous
//
#include <hip/hip_runtime.h>
#include <hip/hip_bf16.h>

#define N_NODES 50000
#define N_EDGES 800000
#define D 128
#define LABEL_DIM 32
#define REL_DIM 32
#define REL_BUCKETS 1024
#define NUM_LABELS 1000
#define LN_EPS 1e-5f

#define SCAN_TILE 1024
#define N_SCAN_BLOCKS ((N_NODES + SCAN_TILE - 1) / SCAN_TILE)  // 49

#define NB 196     // dst buckets of 256 nodes: (50000+255)/256
#define EPB 4096   // edges per bin_scatter block (16/thread)

typedef short bf16x8 __attribute__((ext_vector_type(8)));
typedef float f32x4 __attribute__((ext_vector_type(4)));

__device__ inline unsigned short f2bf(float f) {
    __hip_bfloat16 h = __float2bfloat16(f);
    return *reinterpret_cast<unsigned short*>(&h);
}
__device__ inline float bf2f(unsigned short u) {
    return __uint_as_float((unsigned)u << 16);
}

// ---------------- CSR build ----------------

__global__ __launch_bounds__(256) void count_deg_kernel(const int* __restrict__ dst,
                                                        int* __restrict__ deg) {
    int e = blockIdx.x * 256 + threadIdx.x;
    if (e < N_EDGES) atomicAdd(&deg[dst[e]], 1);
}

__global__ __launch_bounds__(SCAN_TILE) void scan_tiles_kernel(const int* __restrict__ deg,
                                                               int* __restrict__ offsets,
                                                               int* __restrict__ blockSums) {
    __shared__ int buf[SCAN_TILE];
    int i = blockIdx.x * SCAN_TILE + threadIdx.x;
    int v = (i < N_NODES) ? deg[i] : 0;
    buf[threadIdx.x] = v;
    __syncthreads();
    for (int off = 1; off < SCAN_TILE; off <<= 1) {
        int t = (threadIdx.x >= (unsigned)off) ? buf[threadIdx.x - off] : 0;
        __syncthreads();
        buf[threadIdx.x] += t;
        __syncthreads();
    }
    if (i < N_NODES) offsets[i] = buf[threadIdx.x] - v;
    if (threadIdx.x == SCAN_TILE - 1) blockSums[blockIdx.x] = buf[SCAN_TILE - 1];
}

__global__ void scan_sums_kernel(int* __restrict__ blockSums, int* __restrict__ offsets) {
    if (threadIdx.x == 0 && blockIdx.x == 0) {
        int run = 0;
        for (int i = 0; i < N_SCAN_BLOCKS; i++) {
            int v = blockSums[i];
            blockSums[i] = run;
            run += v;
        }
        offsets[N_NODES] = run;
    }
}

__global__ __launch_bounds__(SCAN_TILE) void scan_add_kernel(int* __restrict__ offsets,
                                                             const int* __restrict__ blockSums) {
    int i = blockIdx.x * SCAN_TILE + threadIdx.x;
    if (i < N_NODES) offsets[i] += blockSums[blockIdx.x];
}

// gcur[b] = offsets[b*256] : staged region base for bucket b
__global__ __launch_bounds__(256) void init_gcur_kernel(const int* __restrict__ offsets,
                                                        int* __restrict__ gcur) {
    int b = threadIdx.x + blockIdx.x * 256;
    if (b < NB) gcur[b] = offsets[b * 256];
}

// pass 1: bin edges by dst>>8 into staged arrays (coalesced chunked writes).
// payload: staged_pk = src | rel<<16 ; staged_dl = dst & 255
__global__ __launch_bounds__(256) void bin_scatter_kernel(const int* __restrict__ src,
                                                          const int* __restrict__ dst,
                                                          const int* __restrict__ rel,
                                                          int* __restrict__ gcur,
                                                          unsigned* __restrict__ staged_pk,
                                                          unsigned char* __restrict__ staged_dl) {
    __shared__ int hist[NB];
    __shared__ int lcur[NB];
    const int t = threadIdx.x;
    for (int i = t; i < NB; i += 256) hist[i] = 0;
    __syncthreads();
    const int e0 = blockIdx.x * EPB;
    unsigned char bb[16], dl[16];
#pragma unroll
    for (int i = 0; i < 16; ++i) {
        int e = e0 + i * 256 + t;
        if (e < N_EDGES) {
            int d = dst[e];
            bb[i] = (unsigned char)(d >> 8);
            dl[i] = (unsigned char)(d & 255);
            atomicAdd(&hist[d >> 8], 1);
        }
    }
    __syncthreads();
    for (int b = t; b < NB; b += 256) lcur[b] = atomicAdd(&gcur[b], hist[b]);
    __syncthreads();
#pragma unroll
    for (int i = 0; i < 16; ++i) {
        int e = e0 + i * 256 + t;
        if (e < N_EDGES) {
            int pos = atomicAdd(&lcur[bb[i]], 1);
            staged_pk[pos] = (unsigned)src[e] | ((unsigned)rel[e] << 16);
            staged_dl[pos] = dl[i];
        }
    }
}

// pass 2: one block per bucket; LDS per-node cursors; scatter confined to the
// bucket's ~16KB csr region (single-XCD L2-local -> no write amplification).
__global__ __launch_bounds__(256) void bin_place_kernel(const int* __restrict__ offsets,
                                                        const unsigned* __restrict__ staged_pk,
                                                        const unsigned char* __restrict__ staged_dl,
                                                        unsigned* __restrict__ csr_pk) {
    __shared__ int cur[256];
    __shared__ int s_beg, s_end;
    const int b = blockIdx.x;
    const int t = threadIdx.x;
    const int node0 = b * 256;
    int node = node0 + t;
    cur[t] = (node < N_NODES) ? offsets[node] : 0;
    if (t == 0) s_beg = offsets[node0];
    if (t == 1) s_end = offsets[(node0 + 256 < N_NODES) ? node0 + 256 : N_NODES];
    __syncthreads();
    for (int i = s_beg + t; i < s_end; i += 256) {
        unsigned pk = staged_pk[i];
        int dl = staged_dl[i];
        int pos = atomicAdd(&cur[dl], 1);
        csr_pk[pos] = pk;
    }
}

// ---------------- weight / embedding prep ----------------

__global__ __launch_bounds__(256) void prep_dual_kernel(const float* __restrict__ Wn,
                                                        const float* __restrict__ Ws,
                                                        unsigned short* __restrict__ Bt) {
    int idx = blockIdx.x * 256 + threadIdx.x;  // 256*128 exact
    int n = idx >> 7, k = idx & 127;
    float v = (n < 128) ? Wn[k * 128 + n] : Ws[k * 128 + (n - 128)];
    Bt[idx] = f2bf(v);
}

// Btx[n][k] = in_proj_w[k][n], n<128, k<160
__global__ __launch_bounds__(256) void prep_in_kernel(const float* __restrict__ W,
                                                      unsigned short* __restrict__ Btx) {
    int idx = blockIdx.x * 256 + threadIdx.x;  // 128*160 exact
    int n = idx / 160, k = idx % 160;
    Btx[idx] = f2bf(W[k * 128 + n]);
}

__global__ __launch_bounds__(256) void prep_lemb_kernel(const float* __restrict__ le,
                                                        unsigned short* __restrict__ leb) {
    int i = blockIdx.x * 256 + threadIdx.x;
    if (i < NUM_LABELS * LABEL_DIM) leb[i] = f2bf(le[i]);
}

// ---------------- per-half MFMA GEMM: 128 cols, 32 KiB B-tile -----------------
__global__ __launch_bounds__(256) void mfma_half_kernel(const unsigned short* __restrict__ A,
                                                        const unsigned short* __restrict__ Bt,
                                                        const float* __restrict__ bias,
                                                        unsigned short* __restrict__ outHW,
                                                        unsigned short* __restrict__ outHS) {
    __shared__ unsigned short sB[128 * 128];  // 32 KiB
    const int t = threadIdx.x;
    const unsigned short* Bsrc = Bt + (size_t)blockIdx.y * 128 * 128;
#pragma unroll
    for (int i = 0; i < 8; ++i) {
        int c = t + i * 256;  // 2048 chunks
        int col = c >> 4, kch = c & 15;
        int dstc = col * 16 + (kch ^ (col & 7));
        *(bf16x8*)&sB[dstc * 8] = *(const bf16x8*)&Bsrc[c * 8];
    }
    __syncthreads();

    const int wave = t >> 6, lane = t & 63;
    const int m16 = lane & 15, q = lane >> 4;
    const int r0 = blockIdx.x * 64 + wave * 16;
    const int arow = r0 + m16;
    const bool avalid = arow < N_NODES;
    const unsigned short* ap = A + (size_t)(avalid ? arow : 0) * 128 + q * 8;

    f32x4 acc[8];
#pragma unroll
    for (int ct = 0; ct < 8; ++ct) acc[ct] = (f32x4){0.f, 0.f, 0.f, 0.f};

#pragma unroll
    for (int ki = 0; ki < 4; ++ki) {
        bf16x8 af = *(const bf16x8*)(ap + ki * 32);
        if (!avalid) af = (bf16x8){0, 0, 0, 0, 0, 0, 0, 0};
        int kch = ki * 4 + q;
#pragma unroll
        for (int ct = 0; ct < 8; ++ct) {
            int col = ct * 16 + m16;
            int chunk = col * 16 + (kch ^ (m16 & 7));
            bf16x8 bf = *(const bf16x8*)&sB[chunk * 8];
            acc[ct] = __builtin_amdgcn_mfma_f32_16x16x32_bf16(af, bf, acc[ct], 0, 0, 0);
        }
    }

    if (blockIdx.y == 0) {
#pragma unroll
        for (int ct = 0; ct < 8; ++ct) {
            int colg = ct * 16 + m16;
#pragma unroll
            for (int r = 0; r < 4; ++r) {
                int row = r0 + q * 4 + r;
                if (row < N_NODES) outHW[(size_t)row * 128 + colg] = f2bf(acc[ct][r]);
            }
        }
    } else {
#pragma unroll
        for (int ct = 0; ct < 8; ++ct) {
            int colg = ct * 16 + m16;
            float bs = bias[colg];
#pragma unroll
            for (int r = 0; r < 4; ++r) {
                int row = r0 + q * 4 + r;
                if (row < N_NODES) outHS[(size_t)row * 128 + colg] = f2bf(acc[ct][r] + bs);
            }
        }
    }
}

// ---------------- input-proj MFMA GEMM (fp32 A, K=160, fused lemb+bias+relu) ----
__global__ __launch_bounds__(256) void mfma_in_kernel(const float* __restrict__ X,
                                                      const unsigned short* __restrict__ Btx,
                                                      const unsigned short* __restrict__ leb,
                                                      const int* __restrict__ label,
                                                      const float* __restrict__ bias,
                                                      unsigned short* __restrict__ outBF) {
    __shared__ unsigned short sB[128 * 160];  // 40 KiB; [col][20 chunks of 8]
    const int t = threadIdx.x;
#pragma unroll
    for (int i = 0; i < 10; ++i) {
        int c = t + i * 256;
        int col = c / 20, kch = c % 20;
        int dstc = col * 20 + (kch < 16 ? (kch ^ (col & 7)) : kch);
        *(bf16x8*)&sB[dstc * 8] = *(const bf16x8*)&Btx[c * 8];
    }
    __syncthreads();

    const int wave = t >> 6, lane = t & 63;
    const int m16 = lane & 15, q = lane >> 4;
    const int r0 = blockIdx.x * 64 + wave * 16;
    const int arow = r0 + m16;
    const bool avalid = arow < N_NODES;
    const float* xp = X + (size_t)(avalid ? arow : 0) * 128 + q * 8;

    f32x4 acc[8];
#pragma unroll
    for (int ct = 0; ct < 8; ++ct) acc[ct] = (f32x4){0.f, 0.f, 0.f, 0.f};

#pragma unroll
    for (int ki = 0; ki < 4; ++ki) {
        bf16x8 af;
        if (avalid) {
            float4 v0 = *(const float4*)(xp + ki * 32);
            float4 v1 = *(const float4*)(xp + ki * 32 + 4);
            af[0] = (short)f2bf(v0.x); af[1] = (short)f2bf(v0.y);
            af[2] = (short)f2bf(v0.z); af[3] = (short)f2bf(v0.w);
            af[4] = (short)f2bf(v1.x); af[5] = (short)f2bf(v1.y);
            af[6] = (short)f2bf(v1.z); af[7] = (short)f2bf(v1.w);
        } else {
            af = (bf16x8){0, 0, 0, 0, 0, 0, 0, 0};
        }
        int kch = ki * 4 + q;
#pragma unroll
        for (int ct = 0; ct < 8; ++ct) {
            int col = ct * 16 + m16;
            int chunk = col * 20 + (kch ^ (m16 & 7));
            bf16x8 bf = *(const bf16x8*)&sB[chunk * 8];
            acc[ct] = __builtin_amdgcn_mfma_f32_16x16x32_bf16(af, bf, acc[ct], 0, 0, 0);
        }
    }
    {   // label-embedding K-chunk (k = 128..159)
        int lb = avalid ? label[arow] : 0;
        bf16x8 af = *(const bf16x8*)(leb + (size_t)lb * LABEL_DIM + q * 8);
        if (!avalid) af = (bf16x8){0, 0, 0, 0, 0, 0, 0, 0};
        int kch = 16 + q;
#pragma unroll
        for (int ct = 0; ct < 8; ++ct) {
            int col = ct * 16 + m16;
            int chunk = col * 20 + kch;
            bf16x8 bf = *(const bf16x8*)&sB[chunk * 8];
            acc[ct] = __builtin_amdgcn_mfma_f32_16x16x32_bf16(af, bf, acc[ct], 0, 0, 0);
        }
    }

#pragma unroll
    for (int ct = 0; ct < 8; ++ct) {
        int colg = ct * 16 + m16;
        float bs = bias[colg];
#pragma unroll
        for (int r = 0; r < 4; ++r) {
            int row = r0 + q * 4 + r;
            if (row < N_NODES) {
                float v = fmaxf(acc[ct][r] + bs, 0.f);
                outBF[(size_t)row * 128 + colg] = f2bf(v);
            }
        }
    }
}

// ---------------- relW[1024,128] (bf16) = rel_emb[l] @ lin_rel_w[l] ----------------
__global__ __launch_bounds__(256) void relw_kernel(const float* __restrict__ rel_emb,
                                                   const float* __restrict__ Wr,
                                                   unsigned short* __restrict__ relW) {
    __shared__ float sw[REL_DIM * 128];
    for (int i = threadIdx.x; i < REL_DIM * 128; i += 256) sw[i] = Wr[i];
    __syncthreads();
    int idx = blockIdx.x * 256 + threadIdx.x;  // 1024*128 exact
    int r = idx >> 7, c = idx & 127;
    const float* re = rel_emb + (size_t)r * REL_DIM;
    float a = 0.f;
#pragma unroll
    for (int k = 0; k < REL_DIM; k++) a = fmaf(re[k], sw[k * 128 + c], a);
    relW[idx] = f2bf(a);
}

// ---------------- edge gather + mean + self + relu + layernorm ----------------
template <bool WF32, bool WBF16>
__global__ __launch_bounds__(256) void agg_ln_kernel(const unsigned short* __restrict__ hW,
                                                     const unsigned short* __restrict__ relW,
                                                     const unsigned short* __restrict__ hsb,
                                                     const int* __restrict__ offsets,
                                                     const unsigned* __restrict__ csr_pk,
                                                     const float* __restrict__ g,
                                                     const float* __restrict__ b,
                                                     float* __restrict__ h,
                                                     unsigned short* __restrict__ hb) {
    const int wave = threadIdx.x >> 6;
    const int lane = threadIdx.x & 63;
    const int node = blockIdx.x * 4 + wave;
    if (node >= N_NODES) return;
    const int q = lane >> 4, l16 = lane & 15;
    const int beg = offsets[node], end = offsets[node + 1];
    const int co = l16 * 8;  // column base for this lane

    float acc[8];
#pragma unroll
    for (int j = 0; j < 8; ++j) acc[j] = 0.f;

    for (int e = beg; e < end; e += 4) {
        int idx = e + q;
        float m = 1.f;
        if (idx >= end) { idx = e; m = 0.f; }
        unsigned pk = csr_pk[idx];
        unsigned s = pk & 0xffffu;
        unsigned r = pk >> 16;
        bf16x8 hv = *(const bf16x8*)(hW + ((size_t)s << 7) + co);
        bf16x8 rv = *(const bf16x8*)(relW + ((size_t)r << 7) + co);
#pragma unroll
        for (int j = 0; j < 8; ++j) {
            float val = bf2f((unsigned short)hv[j]) + bf2f((unsigned short)rv[j]);
            acc[j] = fmaf(m, val, acc[j]);
        }
    }
#pragma unroll
    for (int j = 0; j < 8; ++j) {
        acc[j] += __shfl_xor(acc[j], 16);
        acc[j] += __shfl_xor(acc[j], 32);
    }

    float inv = (end > beg) ? 1.f / (float)(end - beg) : 0.f;
    bf16x8 hsv = *(const bf16x8*)(hsb + ((size_t)node << 7) + co);
    float v[8];
    float s_sum = 0.f;
#pragma unroll
    for (int j = 0; j < 8; ++j) {
        v[j] = fmaxf(bf2f((unsigned short)hsv[j]) + acc[j] * inv, 0.f);
        s_sum += v[j];
    }
#pragma unroll
    for (int o = 8; o > 0; o >>= 1) s_sum += __shfl_xor(s_sum, o);
    float mu = s_sum * (1.f / 128.f);
    float qs = 0.f;
    float d[8];
#pragma unroll
    for (int j = 0; j < 8; ++j) {
        d[j] = v[j] - mu;
        qs += d[j] * d[j];
    }
#pragma unroll
    for (int o = 8; o > 0; o >>= 1) qs += __shfl_xor(qs, o);
    float rstd = rsqrtf(qs * (1.f / 128.f) + LN_EPS);

    if (q == 0) {
        float4 g0 = *(const float4*)(g + co), g1 = *(const float4*)(g + co + 4);
        float4 b0 = *(const float4*)(b + co), b1 = *(const float4*)(b + co + 4);
        float o0 = d[0] * rstd * g0.x + b0.x;
        float o1 = d[1] * rstd * g0.y + b0.y;
        float o2 = d[2] * rstd * g0.z + b0.z;
        float o3 = d[3] * rstd * g0.w + b0.w;
        float o4 = d[4] * rstd * g1.x + b1.x;
        float o5 = d[5] * rstd * g1.y + b1.y;
        float o6 = d[6] * rstd * g1.z + b1.z;
        float o7 = d[7] * rstd * g1.w + b1.w;
        if (WF32) {
            *(float4*)(h + ((size_t)node << 7) + co) = make_float4(o0, o1, o2, o3);
            *(float4*)(h + ((size_t)node << 7) + co + 4) = make_float4(o4, o5, o6, o7);
        }
        if (WBF16) {
            bf16x8 ob;
            ob[0] = (short)f2bf(o0); ob[1] = (short)f2bf(o1);
            ob[2] = (short)f2bf(o2); ob[3] = (short)f2bf(o3);
            ob[4] = (short)f2bf(o4); ob[5] = (short)f2bf(o5);
            ob[6] = (short)f2bf(o6); ob[7] = (short)f2bf(o7);
            *(bf16x8*)(hb + ((size_t)node << 7) + co) = ob;
        }
    }
}

// ---------------- launch ----------------

extern "C" void kernel_launch(void* const* d_in, const int* in_sizes, int n_in,
                              void* d_out, int out_size, void* d_ws, size_t ws_size,
                              hipStream_t stream) {
    const float* x          = (const float*)d_in[0];
    const int*   label      = (const int*)d_in[1];
    const int*   edge_index = (const int*)d_in[2];
    const int*   edge_rel   = (const int*)d_in[3];
    const float* label_emb  = (const float*)d_in[4];
    const float* in_proj_w  = (const float*)d_in[5];
    const float* in_proj_b  = (const float*)d_in[6];
    const float* rel_emb    = (const float*)d_in[7];
    const float* lin_neigh_w = (const float*)d_in[8];
    const float* lin_self_w  = (const float*)d_in[9];
    const float* lin_self_b  = (const float*)d_in[10];
    const float* lin_rel_w   = (const float*)d_in[11];
    const float* ln_g        = (const float*)d_in[12];
    const float* ln_b        = (const float*)d_in[13];
    float* h = (float*)d_out;

    char* p = (char*)d_ws;
    auto alloc = [&](size_t bytes) {
        char* r = p;
        p += (bytes + 255) & ~(size_t)255;
        return r;
    };
    int* deg       = (int*)alloc((size_t)N_NODES * 4);
    int* offsets   = (int*)alloc((size_t)(N_NODES + 1) * 4);
    int* blockSums = (int*)alloc((size_t)N_SCAN_BLOCKS * 4);
    int* gcur      = (int*)alloc((size_t)NB * 4);
    unsigned* csr_pk = (unsigned*)alloc((size_t)N_EDGES * 4);
    unsigned* staged_pk = (unsigned*)alloc((size_t)N_EDGES * 4);
    unsigned char* staged_dl = (unsigned char*)alloc((size_t)N_EDGES);
    unsigned short* hW   = (unsigned short*)alloc((size_t)N_NODES * 128 * 2);
    unsigned short* hsb  = (unsigned short*)alloc((size_t)N_NODES * 128 * 2);
    unsigned short* relW = (unsigned short*)alloc((size_t)REL_BUCKETS * 128 * 2);
    unsigned short* hb   = (unsigned short*)alloc((size_t)N_NODES * 128 * 2);
    unsigned short* Bt   = (unsigned short*)alloc((size_t)256 * 128 * 2);
    unsigned short* Btx  = (unsigned short*)alloc((size_t)128 * 160 * 2);
    unsigned short* leb  = (unsigned short*)alloc((size_t)NUM_LABELS * LABEL_DIM * 2);

    const int* src = edge_index;
    const int* dst = edge_index + N_EDGES;

    // CSR build: count -> scan -> bucket-scatter -> bucket-place
    hipMemsetAsync(deg, 0, (size_t)N_NODES * 4, stream);
    count_deg_kernel<<<(N_EDGES + 255) / 256, 256, 0, stream>>>(dst, deg);
    scan_tiles_kernel<<<N_SCAN_BLOCKS, SCAN_TILE, 0, stream>>>(deg, offsets, blockSums);
    scan_sums_kernel<<<1, 64, 0, stream>>>(blockSums, offsets);
    scan_add_kernel<<<N_SCAN_BLOCKS, SCAN_TILE, 0, stream>>>(offsets, blockSums);
    init_gcur_kernel<<<1, 256, 0, stream>>>(offsets, gcur);
    bin_scatter_kernel<<<(N_EDGES + EPB - 1) / EPB, 256, 0, stream>>>(
        src, dst, edge_rel, gcur, staged_pk, staged_dl);
    bin_place_kernel<<<NB, 256, 0, stream>>>(offsets, staged_pk, staged_dl, csr_pk);

    const int gemm_grid = (N_NODES + 63) / 64;  // 782

    // input projection: hb = relu([x | label_emb[label]] @ in_proj_w + b)  (bf16)
    prep_in_kernel<<<(128 * 160) / 256, 256, 0, stream>>>(in_proj_w, Btx);
    prep_lemb_kernel<<<(NUM_LABELS * LABEL_DIM + 255) / 256, 256, 0, stream>>>(label_emb, leb);
    mfma_in_kernel<<<gemm_grid, 256, 0, stream>>>(x, Btx, leb, label, in_proj_b, hb);

    for (int l = 0; l < 2; l++) {
        relw_kernel<<<(REL_BUCKETS * 128) / 256, 256, 0, stream>>>(
            rel_emb + (size_t)l * REL_BUCKETS * REL_DIM, lin_rel_w + (size_t)l * REL_DIM * 128,
            relW);
        prep_dual_kernel<<<(256 * 128) / 256, 256, 0, stream>>>(
            lin_neigh_w + (size_t)l * 128 * 128, lin_self_w + (size_t)l * 128 * 128, Bt);
        mfma_half_kernel<<<dim3(gemm_grid, 2), 256, 0, stream>>>(
            hb, Bt, lin_self_b + (size_t)l * 128, hW, hsb);
        if (l == 0) {
            agg_ln_kernel<false, true><<<(N_NODES + 3) / 4, 256, 0, stream>>>(
                hW, relW, hsb, offsets, csr_pk, ln_g, ln_b, h, hb);
        } else {
            agg_ln_kernel<true, false><<<(N_NODES + 3) / 4, 256, 0, stream>>>(
                hW, relW, hsb, offsets, csr_pk, ln_g + 128, ln_b + 128, h, hb);
        }
    }
}

// Round 8
// 297.222 us; speedup vs baseline: 2.6602x; 1.1228x over previous
//
#include <hip/hip_runtime.h>
#include <hip/hip_bf16.h>

#define N_NODES 50000
#define N_EDGES 800000
#define D 128
#define LABEL_DIM 32
#define REL_DIM 32
#define REL_BUCKETS 1024
#define NUM_LABELS 1000
#define LN_EPS 1e-5f

#define NB 196     // dst buckets of 256 nodes
#define EPB 4096   // edges per bin_scatter block

typedef short bf16x8 __attribute__((ext_vector_type(8)));
typedef float f32x4 __attribute__((ext_vector_type(4)));

__device__ inline unsigned short f2bf(float f) {
    __hip_bfloat16 h = __float2bfloat16(f);
    return *reinterpret_cast<unsigned short*>(&h);
}
__device__ inline float bf2f(unsigned short u) {
    return __uint_as_float((unsigned)u << 16);
}

// ---------------- CSR build (bucketed, no global per-node atomics) ----------------

// per-block LDS histogram of dst>>8 -> 196 global counters
__global__ __launch_bounds__(256) void bucket_count_kernel(const int* __restrict__ dst,
                                                           int* __restrict__ gbh) {
    __shared__ int hsh[NB];
    const int t = threadIdx.x;
    for (int i = t; i < NB; i += 256) hsh[i] = 0;
    __syncthreads();
    for (int e = blockIdx.x * 256 + t; e < N_EDGES; e += gridDim.x * 256)
        atomicAdd(&hsh[dst[e] >> 8], 1);
    __syncthreads();
    for (int i = t; i < NB; i += 256)
        if (hsh[i]) atomicAdd(&gbh[i], hsh[i]);
}

// single block: exclusive scan of 196 bucket counts -> bucket_off[0..NB], gcur
__global__ __launch_bounds__(256) void bucket_scan_kernel(const int* __restrict__ gbh,
                                                          int* __restrict__ bucket_off,
                                                          int* __restrict__ gcur) {
    __shared__ int buf[256];
    const int t = threadIdx.x;
    int v = (t < NB) ? gbh[t] : 0;
    buf[t] = v;
    __syncthreads();
    for (int off = 1; off < 256; off <<= 1) {
        int tv = (t >= off) ? buf[t - off] : 0;
        __syncthreads();
        buf[t] += tv;
        __syncthreads();
    }
    int excl = buf[t] - v;
    if (t < NB) {
        bucket_off[t] = excl;
        gcur[t] = excl;
    }
    if (t == NB - 1) bucket_off[NB] = excl + v;
}

// pass 1: bin edges by dst>>8 into staged arrays (coalesced chunked writes)
__global__ __launch_bounds__(256) void bin_scatter_kernel(const int* __restrict__ src,
                                                          const int* __restrict__ dst,
                                                          const int* __restrict__ rel,
                                                          int* __restrict__ gcur,
                                                          unsigned* __restrict__ staged_pk,
                                                          unsigned char* __restrict__ staged_dl) {
    __shared__ int hist[NB];
    __shared__ int lcur[NB];
    const int t = threadIdx.x;
    for (int i = t; i < NB; i += 256) hist[i] = 0;
    __syncthreads();
    const int e0 = blockIdx.x * EPB;
    unsigned char bb[16], dl[16];
#pragma unroll
    for (int i = 0; i < 16; ++i) {
        int e = e0 + i * 256 + t;
        if (e < N_EDGES) {
            int d = dst[e];
            bb[i] = (unsigned char)(d >> 8);
            dl[i] = (unsigned char)(d & 255);
            atomicAdd(&hist[d >> 8], 1);
        }
    }
    __syncthreads();
    for (int b = t; b < NB; b += 256) lcur[b] = atomicAdd(&gcur[b], hist[b]);
    __syncthreads();
#pragma unroll
    for (int i = 0; i < 16; ++i) {
        int e = e0 + i * 256 + t;
        if (e < N_EDGES) {
            int pos = atomicAdd(&lcur[bb[i]], 1);
            staged_pk[pos] = (unsigned)src[e] | ((unsigned)rel[e] << 16);
            staged_dl[pos] = dl[i];
        }
    }
}

// pass 2: per bucket: LDS node histogram + LDS scan -> per-node offsets[] AND
// edge placement, all confined to the bucket's csr region.
__global__ __launch_bounds__(256) void bin_place2_kernel(const int* __restrict__ bucket_off,
                                                         const unsigned* __restrict__ staged_pk,
                                                         const unsigned char* __restrict__ staged_dl,
                                                         int* __restrict__ offsets,
                                                         unsigned* __restrict__ csr_pk) {
    __shared__ int hist[256];
    __shared__ int buf[256];
    __shared__ int cur[256];
    const int b = blockIdx.x;
    const int t = threadIdx.x;
    const int beg = bucket_off[b], end = bucket_off[b + 1];
    hist[t] = 0;
    __syncthreads();
    for (int i = beg + t; i < end; i += 256) atomicAdd(&hist[staged_dl[i]], 1);
    __syncthreads();
    int v = hist[t];
    buf[t] = v;
    __syncthreads();
    for (int off = 1; off < 256; off <<= 1) {
        int tv = (t >= off) ? buf[t - off] : 0;
        __syncthreads();
        buf[t] += tv;
        __syncthreads();
    }
    int node_off = beg + buf[t] - v;  // exclusive within bucket
    int node = b * 256 + t;
    if (node < N_NODES) offsets[node] = node_off;
    if (b == NB - 1 && t == 0) offsets[N_NODES] = end;
    cur[t] = node_off;
    __syncthreads();
    for (int i = beg + t; i < end; i += 256) {
        int pos = atomicAdd(&cur[staged_dl[i]], 1);
        csr_pk[pos] = staged_pk[i];
    }
}

// ---------------- fused weight/embedding prep (one dispatch) ----------------
#define PB_IN 80      // 128*160/256
#define PB_LEMB 125   // 32000/256
#define PB_DUAL 128   // 256*128/256
#define PB_RELW 512   // 1024*128/256

__global__ __launch_bounds__(256) void prep_all_kernel(
    const float* __restrict__ in_proj_w, const float* __restrict__ label_emb,
    const float* __restrict__ lin_neigh_w, const float* __restrict__ lin_self_w,
    const float* __restrict__ rel_emb, const float* __restrict__ lin_rel_w,
    unsigned short* __restrict__ Btx, unsigned short* __restrict__ leb,
    unsigned short* __restrict__ Bt0, unsigned short* __restrict__ Bt1,
    unsigned short* __restrict__ relW0, unsigned short* __restrict__ relW1) {
    int bb = blockIdx.x;
    const int t = threadIdx.x;
    if (bb < PB_IN) {  // Btx[n][k] = in_proj_w[k][n], k<160
        int idx = bb * 256 + t;
        int n = idx / 160, k = idx % 160;
        Btx[idx] = f2bf(in_proj_w[k * 128 + n]);
        return;
    }
    bb -= PB_IN;
    if (bb < PB_LEMB) {
        int i = bb * 256 + t;
        if (i < NUM_LABELS * LABEL_DIM) leb[i] = f2bf(label_emb[i]);
        return;
    }
    bb -= PB_LEMB;
    if (bb < 2 * PB_DUAL) {  // Bt[n][k] = [Wn|Ws][k][n]
        int l = bb >= PB_DUAL;
        if (l) bb -= PB_DUAL;
        int idx = bb * 256 + t;
        int n = idx >> 7, k = idx & 127;
        const float* Wn = lin_neigh_w + (size_t)l * 128 * 128;
        const float* Ws = lin_self_w + (size_t)l * 128 * 128;
        float v = (n < 128) ? Wn[k * 128 + n] : Ws[k * 128 + (n - 128)];
        (l ? Bt1 : Bt0)[idx] = f2bf(v);
        return;
    }
    bb -= 2 * PB_DUAL;
    {  // relW[l][r][c] = rel_emb[l][r] . lin_rel_w[l][:,c]
        int l = bb >= PB_RELW;
        if (l) bb -= PB_RELW;
        const float* re_base = rel_emb + (size_t)l * REL_BUCKETS * REL_DIM;
        const float* Wr = lin_rel_w + (size_t)l * REL_DIM * 128;
        unsigned short* out = l ? relW1 : relW0;
        __shared__ float sw[REL_DIM * 128];
        for (int i = t; i < REL_DIM * 128; i += 256) sw[i] = Wr[i];
        __syncthreads();
        int idx = bb * 256 + t;
        int r = idx >> 7, c = idx & 127;
        const float* re = re_base + (size_t)r * REL_DIM;
        float a = 0.f;
#pragma unroll
        for (int k = 0; k < REL_DIM; k++) a = fmaf(re[k], sw[k * 128 + c], a);
        out[idx] = f2bf(a);
    }
}

// ---------------- per-half MFMA GEMM: 128 cols, 32 KiB B-tile -----------------
__global__ __launch_bounds__(256) void mfma_half_kernel(const unsigned short* __restrict__ A,
                                                        const unsigned short* __restrict__ Bt,
                                                        const float* __restrict__ bias,
                                                        unsigned short* __restrict__ outHW,
                                                        unsigned short* __restrict__ outHS) {
    __shared__ unsigned short sB[128 * 128];  // 32 KiB
    const int t = threadIdx.x;
    const unsigned short* Bsrc = Bt + (size_t)blockIdx.y * 128 * 128;
#pragma unroll
    for (int i = 0; i < 8; ++i) {
        int c = t + i * 256;
        int col = c >> 4, kch = c & 15;
        int dstc = col * 16 + (kch ^ (col & 7));
        *(bf16x8*)&sB[dstc * 8] = *(const bf16x8*)&Bsrc[c * 8];
    }
    __syncthreads();

    const int wave = t >> 6, lane = t & 63;
    const int m16 = lane & 15, q = lane >> 4;
    const int r0 = blockIdx.x * 64 + wave * 16;
    const int arow = r0 + m16;
    const bool avalid = arow < N_NODES;
    const unsigned short* ap = A + (size_t)(avalid ? arow : 0) * 128 + q * 8;

    f32x4 acc[8];
#pragma unroll
    for (int ct = 0; ct < 8; ++ct) acc[ct] = (f32x4){0.f, 0.f, 0.f, 0.f};

#pragma unroll
    for (int ki = 0; ki < 4; ++ki) {
        bf16x8 af = *(const bf16x8*)(ap + ki * 32);
        if (!avalid) af = (bf16x8){0, 0, 0, 0, 0, 0, 0, 0};
        int kch = ki * 4 + q;
#pragma unroll
        for (int ct = 0; ct < 8; ++ct) {
            int col = ct * 16 + m16;
            int chunk = col * 16 + (kch ^ (m16 & 7));
            bf16x8 bf = *(const bf16x8*)&sB[chunk * 8];
            acc[ct] = __builtin_amdgcn_mfma_f32_16x16x32_bf16(af, bf, acc[ct], 0, 0, 0);
        }
    }

    if (blockIdx.y == 0) {
#pragma unroll
        for (int ct = 0; ct < 8; ++ct) {
            int colg = ct * 16 + m16;
#pragma unroll
            for (int r = 0; r < 4; ++r) {
                int row = r0 + q * 4 + r;
                if (row < N_NODES) outHW[(size_t)row * 128 + colg] = f2bf(acc[ct][r]);
            }
        }
    } else {
#pragma unroll
        for (int ct = 0; ct < 8; ++ct) {
            int colg = ct * 16 + m16;
            float bs = bias[colg];
#pragma unroll
            for (int r = 0; r < 4; ++r) {
                int row = r0 + q * 4 + r;
                if (row < N_NODES) outHS[(size_t)row * 128 + colg] = f2bf(acc[ct][r] + bs);
            }
        }
    }
}

// ---------------- input-proj MFMA GEMM (fp32 A, K=160, fused lemb+bias+relu) ----
__global__ __launch_bounds__(256) void mfma_in_kernel(const float* __restrict__ X,
                                                      const unsigned short* __restrict__ Btx,
                                                      const unsigned short* __restrict__ leb,
                                                      const int* __restrict__ label,
                                                      const float* __restrict__ bias,
                                                      unsigned short* __restrict__ outBF) {
    __shared__ unsigned short sB[128 * 160];  // 40 KiB
    const int t = threadIdx.x;
#pragma unroll
    for (int i = 0; i < 10; ++i) {
        int c = t + i * 256;
        int col = c / 20, kch = c % 20;
        int dstc = col * 20 + (kch < 16 ? (kch ^ (col & 7)) : kch);
        *(bf16x8*)&sB[dstc * 8] = *(const bf16x8*)&Btx[c * 8];
    }
    __syncthreads();

    const int wave = t >> 6, lane = t & 63;
    const int m16 = lane & 15, q = lane >> 4;
    const int r0 = blockIdx.x * 64 + wave * 16;
    const int arow = r0 + m16;
    const bool avalid = arow < N_NODES;
    const float* xp = X + (size_t)(avalid ? arow : 0) * 128 + q * 8;

    f32x4 acc[8];
#pragma unroll
    for (int ct = 0; ct < 8; ++ct) acc[ct] = (f32x4){0.f, 0.f, 0.f, 0.f};

#pragma unroll
    for (int ki = 0; ki < 4; ++ki) {
        bf16x8 af;
        if (avalid) {
            float4 v0 = *(const float4*)(xp + ki * 32);
            float4 v1 = *(const float4*)(xp + ki * 32 + 4);
            af[0] = (short)f2bf(v0.x); af[1] = (short)f2bf(v0.y);
            af[2] = (short)f2bf(v0.z); af[3] = (short)f2bf(v0.w);
            af[4] = (short)f2bf(v1.x); af[5] = (short)f2bf(v1.y);
            af[6] = (short)f2bf(v1.z); af[7] = (short)f2bf(v1.w);
        } else {
            af = (bf16x8){0, 0, 0, 0, 0, 0, 0, 0};
        }
        int kch = ki * 4 + q;
#pragma unroll
        for (int ct = 0; ct < 8; ++ct) {
            int col = ct * 16 + m16;
            int chunk = col * 20 + (kch ^ (m16 & 7));
            bf16x8 bf = *(const bf16x8*)&sB[chunk * 8];
            acc[ct] = __builtin_amdgcn_mfma_f32_16x16x32_bf16(af, bf, acc[ct], 0, 0, 0);
        }
    }
    {  // label-embedding K-chunk (k = 128..159)
        int lb = avalid ? label[arow] : 0;
        bf16x8 af = *(const bf16x8*)(leb + (size_t)lb * LABEL_DIM + q * 8);
        if (!avalid) af = (bf16x8){0, 0, 0, 0, 0, 0, 0, 0};
        int kch = 16 + q;
#pragma unroll
        for (int ct = 0; ct < 8; ++ct) {
            int col = ct * 16 + m16;
            int chunk = col * 20 + kch;
            bf16x8 bf = *(const bf16x8*)&sB[chunk * 8];
            acc[ct] = __builtin_amdgcn_mfma_f32_16x16x32_bf16(af, bf, acc[ct], 0, 0, 0);
        }
    }

#pragma unroll
    for (int ct = 0; ct < 8; ++ct) {
        int colg = ct * 16 + m16;
        float bs = bias[colg];
#pragma unroll
        for (int r = 0; r < 4; ++r) {
            int row = r0 + q * 4 + r;
            if (row < N_NODES) {
                float v = fmaxf(acc[ct][r] + bs, 0.f);
                outBF[(size_t)row * 128 + colg] = f2bf(v);
            }
        }
    }
}

// ---------------- edge gather + mean + self + relu + layernorm ----------------
template <bool WF32, bool WBF16>
__global__ __launch_bounds__(256) void agg_ln_kernel(const unsigned short* __restrict__ hW,
                                                     const unsigned short* __restrict__ relW,
                                                     const unsigned short* __restrict__ hsb,
                                                     const int* __restrict__ offsets,
                                                     const unsigned* __restrict__ csr_pk,
                                                     const float* __restrict__ g,
                                                     const float* __restrict__ b,
                                                     float* __restrict__ h,
                                                     unsigned short* __restrict__ hb) {
    const int wave = threadIdx.x >> 6;
    const int lane = threadIdx.x & 63;
    const int node = blockIdx.x * 4 + wave;
    if (node >= N_NODES) return;
    const int q = lane >> 4, l16 = lane & 15;
    const int beg = offsets[node], end = offsets[node + 1];
    const int co = l16 * 8;

    float acc[8];
#pragma unroll
    for (int j = 0; j < 8; ++j) acc[j] = 0.f;

    for (int e = beg; e < end; e += 4) {
        int idx = e + q;
        float m = 1.f;
        if (idx >= end) { idx = e; m = 0.f; }
        unsigned pk = csr_pk[idx];
        unsigned s = pk & 0xffffu;
        unsigned r = pk >> 16;
        bf16x8 hv = *(const bf16x8*)(hW + ((size_t)s << 7) + co);
        bf16x8 rv = *(const bf16x8*)(relW + ((size_t)r << 7) + co);
#pragma unroll
        for (int j = 0; j < 8; ++j) {
            float val = bf2f((unsigned short)hv[j]) + bf2f((unsigned short)rv[j]);
            acc[j] = fmaf(m, val, acc[j]);
        }
    }
#pragma unroll
    for (int j = 0; j < 8; ++j) {
        acc[j] += __shfl_xor(acc[j], 16);
        acc[j] += __shfl_xor(acc[j], 32);
    }

    float inv = (end > beg) ? 1.f / (float)(end - beg) : 0.f;
    bf16x8 hsv = *(const bf16x8*)(hsb + ((size_t)node << 7) + co);
    float v[8];
    float s_sum = 0.f;
#pragma unroll
    for (int j = 0; j < 8; ++j) {
        v[j] = fmaxf(bf2f((unsigned short)hsv[j]) + acc[j] * inv, 0.f);
        s_sum += v[j];
    }
#pragma unroll
    for (int o = 8; o > 0; o >>= 1) s_sum += __shfl_xor(s_sum, o);
    float mu = s_sum * (1.f / 128.f);
    float qs = 0.f;
    float d[8];
#pragma unroll
    for (int j = 0; j < 8; ++j) {
        d[j] = v[j] - mu;
        qs += d[j] * d[j];
    }
#pragma unroll
    for (int o = 8; o > 0; o >>= 1) qs += __shfl_xor(qs, o);
    float rstd = rsqrtf(qs * (1.f / 128.f) + LN_EPS);

    if (q == 0) {
        float4 g0 = *(const float4*)(g + co), g1 = *(const float4*)(g + co + 4);
        float4 b0 = *(const float4*)(b + co), b1 = *(const float4*)(b + co + 4);
        float o0 = d[0] * rstd * g0.x + b0.x;
        float o1 = d[1] * rstd * g0.y + b0.y;
        float o2 = d[2] * rstd * g0.z + b0.z;
        float o3 = d[3] * rstd * g0.w + b0.w;
        float o4 = d[4] * rstd * g1.x + b1.x;
        float o5 = d[5] * rstd * g1.y + b1.y;
        float o6 = d[6] * rstd * g1.z + b1.z;
        float o7 = d[7] * rstd * g1.w + b1.w;
        if (WF32) {
            *(float4*)(h + ((size_t)node << 7) + co) = make_float4(o0, o1, o2, o3);
            *(float4*)(h + ((size_t)node << 7) + co + 4) = make_float4(o4, o5, o6, o7);
        }
        if (WBF16) {
            bf16x8 ob;
            ob[0] = (short)f2bf(o0); ob[1] = (short)f2bf(o1);
            ob[2] = (short)f2bf(o2); ob[3] = (short)f2bf(o3);
            ob[4] = (short)f2bf(o4); ob[5] = (short)f2bf(o5);
            ob[6] = (short)f2bf(o6); ob[7] = (short)f2bf(o7);
            *(bf16x8*)(hb + ((size_t)node << 7) + co) = ob;
        }
    }
}

// ---------------- launch ----------------

extern "C" void kernel_launch(void* const* d_in, const int* in_sizes, int n_in,
                              void* d_out, int out_size, void* d_ws, size_t ws_size,
                              hipStream_t stream) {
    const float* x          = (const float*)d_in[0];
    const int*   label      = (const int*)d_in[1];
    const int*   edge_index = (const int*)d_in[2];
    const int*   edge_rel   = (const int*)d_in[3];
    const float* label_emb  = (const float*)d_in[4];
    const float* in_proj_w  = (const float*)d_in[5];
    const float* in_proj_b  = (const float*)d_in[6];
    const float* rel_emb    = (const float*)d_in[7];
    const float* lin_neigh_w = (const float*)d_in[8];
    const float* lin_self_w  = (const float*)d_in[9];
    const float* lin_self_b  = (const float*)d_in[10];
    const float* lin_rel_w   = (const float*)d_in[11];
    const float* ln_g        = (const float*)d_in[12];
    const float* ln_b        = (const float*)d_in[13];
    float* h = (float*)d_out;

    char* p = (char*)d_ws;
    auto alloc = [&](size_t bytes) {
        char* r = p;
        p += (bytes + 255) & ~(size_t)255;
        return r;
    };
    int* gbh        = (int*)alloc((size_t)NB * 4);
    int* bucket_off = (int*)alloc((size_t)(NB + 1) * 4);
    int* gcur       = (int*)alloc((size_t)NB * 4);
    int* offsets    = (int*)alloc((size_t)(N_NODES + 1) * 4);
    unsigned* csr_pk = (unsigned*)alloc((size_t)N_EDGES * 4);
    unsigned* staged_pk = (unsigned*)alloc((size_t)N_EDGES * 4);
    unsigned char* staged_dl = (unsigned char*)alloc((size_t)N_EDGES);
    unsigned short* hW    = (unsigned short*)alloc((size_t)N_NODES * 128 * 2);
    unsigned short* hsb   = (unsigned short*)alloc((size_t)N_NODES * 128 * 2);
    unsigned short* relW0 = (unsigned short*)alloc((size_t)REL_BUCKETS * 128 * 2);
    unsigned short* relW1 = (unsigned short*)alloc((size_t)REL_BUCKETS * 128 * 2);
    unsigned short* hb    = (unsigned short*)alloc((size_t)N_NODES * 128 * 2);
    unsigned short* Bt0   = (unsigned short*)alloc((size_t)256 * 128 * 2);
    unsigned short* Bt1   = (unsigned short*)alloc((size_t)256 * 128 * 2);
    unsigned short* Btx   = (unsigned short*)alloc((size_t)128 * 160 * 2);
    unsigned short* leb   = (unsigned short*)alloc((size_t)NUM_LABELS * LABEL_DIM * 2);

    const int* src = edge_index;
    const int* dst = edge_index + N_EDGES;

    // CSR build: 5 dispatches, no per-node global atomics
    hipMemsetAsync(gbh, 0, (size_t)NB * 4, stream);
    bucket_count_kernel<<<256, 256, 0, stream>>>(dst, gbh);
    bucket_scan_kernel<<<1, 256, 0, stream>>>(gbh, bucket_off, gcur);
    bin_scatter_kernel<<<(N_EDGES + EPB - 1) / EPB, 256, 0, stream>>>(
        src, dst, edge_rel, gcur, staged_pk, staged_dl);
    bin_place2_kernel<<<NB, 256, 0, stream>>>(bucket_off, staged_pk, staged_dl, offsets, csr_pk);

    // all weight/embedding prep in one dispatch
    prep_all_kernel<<<PB_IN + PB_LEMB + 2 * PB_DUAL + 2 * PB_RELW, 256, 0, stream>>>(
        in_proj_w, label_emb, lin_neigh_w, lin_self_w, rel_emb, lin_rel_w,
        Btx, leb, Bt0, Bt1, relW0, relW1);

    const int gemm_grid = (N_NODES + 63) / 64;  // 782

    // input projection: hb = relu([x | label_emb[label]] @ in_proj_w + b)  (bf16)
    mfma_in_kernel<<<gemm_grid, 256, 0, stream>>>(x, Btx, leb, label, in_proj_b, hb);

    // layer 0
    mfma_half_kernel<<<dim3(gemm_grid, 2), 256, 0, stream>>>(hb, Bt0, lin_self_b, hW, hsb);
    agg_ln_kernel<false, true><<<(N_NODES + 3) / 4, 256, 0, stream>>>(
        hW, relW0, hsb, offsets, csr_pk, ln_g, ln_b, h, hb);
    // layer 1
    mfma_half_kernel<<<dim3(gemm_grid, 2), 256, 0, stream>>>(hb, Bt1, lin_self_b + 128, hW, hsb);
    agg_ln_kernel<true, false><<<(N_NODES + 3) / 4, 256, 0, stream>>>(
        hW, relW1, hsb, offsets, csr_pk, ln_g + 128, ln_b + 128, h, hb);
}

// Round 9
// 280.568 us; speedup vs baseline: 2.8181x; 1.0594x over previous
//
#include <hip/hip_runtime.h>
#include <hip/hip_bf16.h>

#define N_NODES 50000
#define N_EDGES 800000
#define D 128
#define LABEL_DIM 32
#define REL_DIM 32
#define REL_BUCKETS 1024
#define NUM_LABELS 1000
#define LN_EPS 1e-5f

#define NB 196     // dst buckets of 256 nodes
#define EPB 1024   // edges per bin_scatter block (4/thread)

typedef short bf16x8 __attribute__((ext_vector_type(8)));
typedef float f32x4 __attribute__((ext_vector_type(4)));

__device__ inline unsigned short f2bf(float f) {
    __hip_bfloat16 h = __float2bfloat16(f);
    return *reinterpret_cast<unsigned short*>(&h);
}
__device__ inline float bf2f(unsigned short u) {
    return __uint_as_float((unsigned)u << 16);
}

// ---------------- CSR build (bucketed, no global per-node atomics) ----------------

__global__ __launch_bounds__(256) void bucket_count_kernel(const int* __restrict__ dst,
                                                           int* __restrict__ gbh) {
    __shared__ int hsh[NB];
    const int t = threadIdx.x;
    for (int i = t; i < NB; i += 256) hsh[i] = 0;
    __syncthreads();
    for (int e = blockIdx.x * 256 + t; e < N_EDGES; e += gridDim.x * 256)
        atomicAdd(&hsh[dst[e] >> 8], 1);
    __syncthreads();
    for (int i = t; i < NB; i += 256)
        if (hsh[i]) atomicAdd(&gbh[i], hsh[i]);
}

__global__ __launch_bounds__(256) void bucket_scan_kernel(const int* __restrict__ gbh,
                                                          int* __restrict__ bucket_off,
                                                          int* __restrict__ gcur) {
    __shared__ int buf[256];
    const int t = threadIdx.x;
    int v = (t < NB) ? gbh[t] : 0;
    buf[t] = v;
    __syncthreads();
    for (int off = 1; off < 256; off <<= 1) {
        int tv = (t >= off) ? buf[t - off] : 0;
        __syncthreads();
        buf[t] += tv;
        __syncthreads();
    }
    int excl = buf[t] - v;
    if (t < NB) {
        bucket_off[t] = excl;
        gcur[t] = excl;
    }
    if (t == NB - 1) bucket_off[NB] = excl + v;
}

// pass 1: bin edges by dst>>8 into staged arrays; 782 blocks for latency hiding
__global__ __launch_bounds__(256) void bin_scatter_kernel(const int* __restrict__ src,
                                                          const int* __restrict__ dst,
                                                          const int* __restrict__ rel,
                                                          int* __restrict__ gcur,
                                                          unsigned* __restrict__ staged_pk,
                                                          unsigned char* __restrict__ staged_dl) {
    __shared__ int hist[NB];
    __shared__ int lcur[NB];
    const int t = threadIdx.x;
    for (int i = t; i < NB; i += 256) hist[i] = 0;
    __syncthreads();
    const int e0 = blockIdx.x * EPB;
    unsigned char bb[4], dl[4];
#pragma unroll
    for (int i = 0; i < 4; ++i) {
        int e = e0 + i * 256 + t;
        if (e < N_EDGES) {
            int d = dst[e];
            bb[i] = (unsigned char)(d >> 8);
            dl[i] = (unsigned char)(d & 255);
            atomicAdd(&hist[d >> 8], 1);
        }
    }
    __syncthreads();
    for (int b = t; b < NB; b += 256) {
        int hc = hist[b];
        lcur[b] = hc ? atomicAdd(&gcur[b], hc) : 0;
    }
    __syncthreads();
#pragma unroll
    for (int i = 0; i < 4; ++i) {
        int e = e0 + i * 256 + t;
        if (e < N_EDGES) {
            int pos = atomicAdd(&lcur[bb[i]], 1);
            staged_pk[pos] = (unsigned)src[e] | ((unsigned)rel[e] << 16);
            staged_dl[pos] = dl[i];
        }
    }
}

// pass 2: per bucket (512 threads = 8 waves): LDS node histogram + scan ->
// per-node offsets[] AND edge placement, confined to the bucket's csr region.
__global__ __launch_bounds__(512) void bin_place2_kernel(const int* __restrict__ bucket_off,
                                                         const unsigned* __restrict__ staged_pk,
                                                         const unsigned char* __restrict__ staged_dl,
                                                         int* __restrict__ offsets,
                                                         unsigned* __restrict__ csr_pk) {
    __shared__ int hist[256];
    __shared__ int buf[512];
    __shared__ int cur[256];
    const int b = blockIdx.x;
    const int t = threadIdx.x;
    const int beg = bucket_off[b], end = bucket_off[b + 1];
    if (t < 256) hist[t] = 0;
    __syncthreads();
    for (int i = beg + t; i < end; i += 512) atomicAdd(&hist[staged_dl[i]], 1);
    __syncthreads();
    int v = (t < 256) ? hist[t] : 0;
    buf[t] = v;
    __syncthreads();
    for (int off = 1; off < 512; off <<= 1) {
        int tv = (t >= off) ? buf[t - off] : 0;
        __syncthreads();
        buf[t] += tv;
        __syncthreads();
    }
    if (t < 256) {
        int node_off = beg + buf[t] - v;
        int node = b * 256 + t;
        if (node < N_NODES) offsets[node] = node_off;
        if (b == NB - 1 && t == 0) offsets[N_NODES] = end;
        cur[t] = node_off;
    }
    __syncthreads();
    for (int i = beg + t; i < end; i += 512) {
        int pos = atomicAdd(&cur[staged_dl[i]], 1);
        csr_pk[pos] = staged_pk[i];
    }
}

// ---------------- fused weight/embedding prep (one dispatch) ----------------
#define PB_IN 80      // 128*160/256
#define PB_LEMB 125   // 32000/256
#define PB_DUAL 128   // 256*128/256
#define PB_RELW 512   // 1024*128/256

__global__ __launch_bounds__(256) void prep_all_kernel(
    const float* __restrict__ in_proj_w, const float* __restrict__ label_emb,
    const float* __restrict__ lin_neigh_w, const float* __restrict__ lin_self_w,
    const float* __restrict__ rel_emb, const float* __restrict__ lin_rel_w,
    unsigned short* __restrict__ Btx, unsigned short* __restrict__ leb,
    unsigned short* __restrict__ Bt0, unsigned short* __restrict__ Bt1,
    unsigned short* __restrict__ relW0, unsigned short* __restrict__ relW1) {
    int bb = blockIdx.x;
    const int t = threadIdx.x;
    if (bb < PB_IN) {
        int idx = bb * 256 + t;
        int n = idx / 160, k = idx % 160;
        Btx[idx] = f2bf(in_proj_w[k * 128 + n]);
        return;
    }
    bb -= PB_IN;
    if (bb < PB_LEMB) {
        int i = bb * 256 + t;
        if (i < NUM_LABELS * LABEL_DIM) leb[i] = f2bf(label_emb[i]);
        return;
    }
    bb -= PB_LEMB;
    if (bb < 2 * PB_DUAL) {
        int l = bb >= PB_DUAL;
        if (l) bb -= PB_DUAL;
        int idx = bb * 256 + t;
        int n = idx >> 7, k = idx & 127;
        const float* Wn = lin_neigh_w + (size_t)l * 128 * 128;
        const float* Ws = lin_self_w + (size_t)l * 128 * 128;
        float v = (n < 128) ? Wn[k * 128 + n] : Ws[k * 128 + (n - 128)];
        (l ? Bt1 : Bt0)[idx] = f2bf(v);
        return;
    }
    bb -= 2 * PB_DUAL;
    {
        int l = bb >= PB_RELW;
        if (l) bb -= PB_RELW;
        const float* re_base = rel_emb + (size_t)l * REL_BUCKETS * REL_DIM;
        const float* Wr = lin_rel_w + (size_t)l * REL_DIM * 128;
        unsigned short* out = l ? relW1 : relW0;
        __shared__ float sw[REL_DIM * 128];
        for (int i = t; i < REL_DIM * 128; i += 256) sw[i] = Wr[i];
        __syncthreads();
        int idx = bb * 256 + t;
        int r = idx >> 7, c = idx & 127;
        const float* re = re_base + (size_t)r * REL_DIM;
        float a = 0.f;
#pragma unroll
        for (int k = 0; k < REL_DIM; k++) a = fmaf(re[k], sw[k * 128 + c], a);
        out[idx] = f2bf(a);
    }
}

// ---------------- per-half MFMA GEMM: 128 cols, 32 KiB B-tile -----------------
__global__ __launch_bounds__(256) void mfma_half_kernel(const unsigned short* __restrict__ A,
                                                        const unsigned short* __restrict__ Bt,
                                                        const float* __restrict__ bias,
                                                        unsigned short* __restrict__ outHW,
                                                        unsigned short* __restrict__ outHS) {
    __shared__ unsigned short sB[128 * 128];  // 32 KiB
    const int t = threadIdx.x;
    const unsigned short* Bsrc = Bt + (size_t)blockIdx.y * 128 * 128;
#pragma unroll
    for (int i = 0; i < 8; ++i) {
        int c = t + i * 256;
        int col = c >> 4, kch = c & 15;
        int dstc = col * 16 + (kch ^ (col & 7));
        *(bf16x8*)&sB[dstc * 8] = *(const bf16x8*)&Bsrc[c * 8];
    }
    __syncthreads();

    const int wave = t >> 6, lane = t & 63;
    const int m16 = lane & 15, q = lane >> 4;
    const int r0 = blockIdx.x * 64 + wave * 16;
    const int arow = r0 + m16;
    const bool avalid = arow < N_NODES;
    const unsigned short* ap = A + (size_t)(avalid ? arow : 0) * 128 + q * 8;

    f32x4 acc[8];
#pragma unroll
    for (int ct = 0; ct < 8; ++ct) acc[ct] = (f32x4){0.f, 0.f, 0.f, 0.f};

#pragma unroll
    for (int ki = 0; ki < 4; ++ki) {
        bf16x8 af = *(const bf16x8*)(ap + ki * 32);
        if (!avalid) af = (bf16x8){0, 0, 0, 0, 0, 0, 0, 0};
        int kch = ki * 4 + q;
#pragma unroll
        for (int ct = 0; ct < 8; ++ct) {
            int col = ct * 16 + m16;
            int chunk = col * 16 + (kch ^ (m16 & 7));
            bf16x8 bf = *(const bf16x8*)&sB[chunk * 8];
            acc[ct] = __builtin_amdgcn_mfma_f32_16x16x32_bf16(af, bf, acc[ct], 0, 0, 0);
        }
    }

    if (blockIdx.y == 0) {
#pragma unroll
        for (int ct = 0; ct < 8; ++ct) {
            int colg = ct * 16 + m16;
#pragma unroll
            for (int r = 0; r < 4; ++r) {
                int row = r0 + q * 4 + r;
                if (row < N_NODES) outHW[(size_t)row * 128 + colg] = f2bf(acc[ct][r]);
            }
        }
    } else {
#pragma unroll
        for (int ct = 0; ct < 8; ++ct) {
            int colg = ct * 16 + m16;
            float bs = bias[colg];
#pragma unroll
            for (int r = 0; r < 4; ++r) {
                int row = r0 + q * 4 + r;
                if (row < N_NODES) outHS[(size_t)row * 128 + colg] = f2bf(acc[ct][r] + bs);
            }
        }
    }
}

// ---------------- input-proj MFMA GEMM (fp32 A, K=160, fused lemb+bias+relu) ----
__global__ __launch_bounds__(256) void mfma_in_kernel(const float* __restrict__ X,
                                                      const unsigned short* __restrict__ Btx,
                                                      const unsigned short* __restrict__ leb,
                                                      const int* __restrict__ label,
                                                      const float* __restrict__ bias,
                                                      unsigned short* __restrict__ outBF) {
    __shared__ unsigned short sB[128 * 160];  // 40 KiB
    const int t = threadIdx.x;
#pragma unroll
    for (int i = 0; i < 10; ++i) {
        int c = t + i * 256;
        int col = c / 20, kch = c % 20;
        int dstc = col * 20 + (kch < 16 ? (kch ^ (col & 7)) : kch);
        *(bf16x8*)&sB[dstc * 8] = *(const bf16x8*)&Btx[c * 8];
    }
    __syncthreads();

    const int wave = t >> 6, lane = t & 63;
    const int m16 = lane & 15, q = lane >> 4;
    const int r0 = blockIdx.x * 64 + wave * 16;
    const int arow = r0 + m16;
    const bool avalid = arow < N_NODES;
    const float* xp = X + (size_t)(avalid ? arow : 0) * 128 + q * 8;

    f32x4 acc[8];
#pragma unroll
    for (int ct = 0; ct < 8; ++ct) acc[ct] = (f32x4){0.f, 0.f, 0.f, 0.f};

#pragma unroll
    for (int ki = 0; ki < 4; ++ki) {
        bf16x8 af;
        if (avalid) {
            float4 v0 = *(const float4*)(xp + ki * 32);
            float4 v1 = *(const float4*)(xp + ki * 32 + 4);
            af[0] = (short)f2bf(v0.x); af[1] = (short)f2bf(v0.y);
            af[2] = (short)f2bf(v0.z); af[3] = (short)f2bf(v0.w);
            af[4] = (short)f2bf(v1.x); af[5] = (short)f2bf(v1.y);
            af[6] = (short)f2bf(v1.z); af[7] = (short)f2bf(v1.w);
        } else {
            af = (bf16x8){0, 0, 0, 0, 0, 0, 0, 0};
        }
        int kch = ki * 4 + q;
#pragma unroll
        for (int ct = 0; ct < 8; ++ct) {
            int col = ct * 16 + m16;
            int chunk = col * 20 + (kch ^ (m16 & 7));
            bf16x8 bf = *(const bf16x8*)&sB[chunk * 8];
            acc[ct] = __builtin_amdgcn_mfma_f32_16x16x32_bf16(af, bf, acc[ct], 0, 0, 0);
        }
    }
    {
        int lb = avalid ? label[arow] : 0;
        bf16x8 af = *(const bf16x8*)(leb + (size_t)lb * LABEL_DIM + q * 8);
        if (!avalid) af = (bf16x8){0, 0, 0, 0, 0, 0, 0, 0};
        int kch = 16 + q;
#pragma unroll
        for (int ct = 0; ct < 8; ++ct) {
            int col = ct * 16 + m16;
            int chunk = col * 20 + kch;
            bf16x8 bf = *(const bf16x8*)&sB[chunk * 8];
            acc[ct] = __builtin_amdgcn_mfma_f32_16x16x32_bf16(af, bf, acc[ct], 0, 0, 0);
        }
    }

#pragma unroll
    for (int ct = 0; ct < 8; ++ct) {
        int colg = ct * 16 + m16;
        float bs = bias[colg];
#pragma unroll
        for (int r = 0; r < 4; ++r) {
            int row = r0 + q * 4 + r;
            if (row < N_NODES) {
                float v = fmaxf(acc[ct][r] + bs, 0.f);
                outBF[(size_t)row * 128 + colg] = f2bf(v);
            }
        }
    }
}

// ---------------- edge gather + mean + self + relu + layernorm ----------------
// One wave per node; quarter q handles edges e+q and e+4+q per iteration (x2
// unroll -> 6 independent loads in flight = 2x MLP). Per-lane accumulation
// order identical to the non-unrolled version.
template <bool WF32, bool WBF16>
__global__ __launch_bounds__(256) void agg_ln_kernel(const unsigned short* __restrict__ hW,
                                                     const unsigned short* __restrict__ relW,
                                                     const unsigned short* __restrict__ hsb,
                                                     const int* __restrict__ offsets,
                                                     const unsigned* __restrict__ csr_pk,
                                                     const float* __restrict__ g,
                                                     const float* __restrict__ b,
                                                     float* __restrict__ h,
                                                     unsigned short* __restrict__ hb) {
    const int wave = threadIdx.x >> 6;
    const int lane = threadIdx.x & 63;
    const int node = blockIdx.x * 4 + wave;
    if (node >= N_NODES) return;
    const int q = lane >> 4, l16 = lane & 15;
    const int beg = offsets[node], end = offsets[node + 1];
    const int co = l16 * 8;

    float acc[8];
#pragma unroll
    for (int j = 0; j < 8; ++j) acc[j] = 0.f;

    for (int e = beg; e < end; e += 8) {
        int i0 = e + q, i1 = e + 4 + q;
        float m0 = 1.f, m1 = 1.f;
        if (i0 >= end) { i0 = beg; m0 = 0.f; }
        if (i1 >= end) { i1 = beg; m1 = 0.f; }
        unsigned pk0 = csr_pk[i0];
        unsigned pk1 = csr_pk[i1];
        bf16x8 hv0 = *(const bf16x8*)(hW + ((size_t)(pk0 & 0xffffu) << 7) + co);
        bf16x8 rv0 = *(const bf16x8*)(relW + ((size_t)(pk0 >> 16) << 7) + co);
        bf16x8 hv1 = *(const bf16x8*)(hW + ((size_t)(pk1 & 0xffffu) << 7) + co);
        bf16x8 rv1 = *(const bf16x8*)(relW + ((size_t)(pk1 >> 16) << 7) + co);
#pragma unroll
        for (int j = 0; j < 8; ++j) {
            float v0 = bf2f((unsigned short)hv0[j]) + bf2f((unsigned short)rv0[j]);
            acc[j] = fmaf(m0, v0, acc[j]);
        }
#pragma unroll
        for (int j = 0; j < 8; ++j) {
            float v1 = bf2f((unsigned short)hv1[j]) + bf2f((unsigned short)rv1[j]);
            acc[j] = fmaf(m1, v1, acc[j]);
        }
    }
#pragma unroll
    for (int j = 0; j < 8; ++j) {
        acc[j] += __shfl_xor(acc[j], 16);
        acc[j] += __shfl_xor(acc[j], 32);
    }

    float inv = (end > beg) ? 1.f / (float)(end - beg) : 0.f;
    bf16x8 hsv = *(const bf16x8*)(hsb + ((size_t)node << 7) + co);
    float v[8];
    float s_sum = 0.f;
#pragma unroll
    for (int j = 0; j < 8; ++j) {
        v[j] = fmaxf(bf2f((unsigned short)hsv[j]) + acc[j] * inv, 0.f);
        s_sum += v[j];
    }
#pragma unroll
    for (int o = 8; o > 0; o >>= 1) s_sum += __shfl_xor(s_sum, o);
    float mu = s_sum * (1.f / 128.f);
    float qs = 0.f;
    float d[8];
#pragma unroll
    for (int j = 0; j < 8; ++j) {
        d[j] = v[j] - mu;
        qs += d[j] * d[j];
    }
#pragma unroll
    for (int o = 8; o > 0; o >>= 1) qs += __shfl_xor(qs, o);
    float rstd = rsqrtf(qs * (1.f / 128.f) + LN_EPS);

    if (q == 0) {
        float4 g0 = *(const float4*)(g + co), g1 = *(const float4*)(g + co + 4);
        float4 b0 = *(const float4*)(b + co), b1 = *(const float4*)(b + co + 4);
        float o0 = d[0] * rstd * g0.x + b0.x;
        float o1 = d[1] * rstd * g0.y + b0.y;
        float o2 = d[2] * rstd * g0.z + b0.z;
        float o3 = d[3] * rstd * g0.w + b0.w;
        float o4 = d[4] * rstd * g1.x + b1.x;
        float o5 = d[5] * rstd * g1.y + b1.y;
        float o6 = d[6] * rstd * g1.z + b1.z;
        float o7 = d[7] * rstd * g1.w + b1.w;
        if (WF32) {
            *(float4*)(h + ((size_t)node << 7) + co) = make_float4(o0, o1, o2, o3);
            *(float4*)(h + ((size_t)node << 7) + co + 4) = make_float4(o4, o5, o6, o7);
        }
        if (WBF16) {
            bf16x8 ob;
            ob[0] = (short)f2bf(o0); ob[1] = (short)f2bf(o1);
            ob[2] = (short)f2bf(o2); ob[3] = (short)f2bf(o3);
            ob[4] = (short)f2bf(o4); ob[5] = (short)f2bf(o5);
            ob[6] = (short)f2bf(o6); ob[7] = (short)f2bf(o7);
            *(bf16x8*)(hb + ((size_t)node << 7) + co) = ob;
        }
    }
}

// ---------------- launch ----------------

extern "C" void kernel_launch(void* const* d_in, const int* in_sizes, int n_in,
                              void* d_out, int out_size, void* d_ws, size_t ws_size,
                              hipStream_t stream) {
    const float* x          = (const float*)d_in[0];
    const int*   label      = (const int*)d_in[1];
    const int*   edge_index = (const int*)d_in[2];
    const int*   edge_rel   = (const int*)d_in[3];
    const float* label_emb  = (const float*)d_in[4];
    const float* in_proj_w  = (const float*)d_in[5];
    const float* in_proj_b  = (const float*)d_in[6];
    const float* rel_emb    = (const float*)d_in[7];
    const float* lin_neigh_w = (const float*)d_in[8];
    const float* lin_self_w  = (const float*)d_in[9];
    const float* lin_self_b  = (const float*)d_in[10];
    const float* lin_rel_w   = (const float*)d_in[11];
    const float* ln_g        = (const float*)d_in[12];
    const float* ln_b        = (const float*)d_in[13];
    float* h = (float*)d_out;

    char* p = (char*)d_ws;
    auto alloc = [&](size_t bytes) {
        char* r = p;
        p += (bytes + 255) & ~(size_t)255;
        return r;
    };
    int* gbh        = (int*)alloc((size_t)NB * 4);
    int* bucket_off = (int*)alloc((size_t)(NB + 1) * 4);
    int* gcur       = (int*)alloc((size_t)NB * 4);
    int* offsets    = (int*)alloc((size_t)(N_NODES + 1) * 4);
    unsigned* csr_pk = (unsigned*)alloc((size_t)N_EDGES * 4);
    unsigned* staged_pk = (unsigned*)alloc((size_t)N_EDGES * 4);
    unsigned char* staged_dl = (unsigned char*)alloc((size_t)N_EDGES);
    unsigned short* hW    = (unsigned short*)alloc((size_t)N_NODES * 128 * 2);
    unsigned short* hsb   = (unsigned short*)alloc((size_t)N_NODES * 128 * 2);
    unsigned short* relW0 = (unsigned short*)alloc((size_t)REL_BUCKETS * 128 * 2);
    unsigned short* relW1 = (unsigned short*)alloc((size_t)REL_BUCKETS * 128 * 2);
    unsigned short* hb    = (unsigned short*)alloc((size_t)N_NODES * 128 * 2);
    unsigned short* Bt0   = (unsigned short*)alloc((size_t)256 * 128 * 2);
    unsigned short* Bt1   = (unsigned short*)alloc((size_t)256 * 128 * 2);
    unsigned short* Btx   = (unsigned short*)alloc((size_t)128 * 160 * 2);
    unsigned short* leb   = (unsigned short*)alloc((size_t)NUM_LABELS * LABEL_DIM * 2);

    const int* src = edge_index;
    const int* dst = edge_index + N_EDGES;

    // CSR build
    hipMemsetAsync(gbh, 0, (size_t)NB * 4, stream);
    bucket_count_kernel<<<784, 256, 0, stream>>>(dst, gbh);
    bucket_scan_kernel<<<1, 256, 0, stream>>>(gbh, bucket_off, gcur);
    bin_scatter_kernel<<<(N_EDGES + EPB - 1) / EPB, 256, 0, stream>>>(
        src, dst, edge_rel, gcur, staged_pk, staged_dl);
    bin_place2_kernel<<<NB, 512, 0, stream>>>(bucket_off, staged_pk, staged_dl, offsets, csr_pk);

    // all weight/embedding prep in one dispatch
    prep_all_kernel<<<PB_IN + PB_LEMB + 2 * PB_DUAL + 2 * PB_RELW, 256, 0, stream>>>(
        in_proj_w, label_emb, lin_neigh_w, lin_self_w, rel_emb, lin_rel_w,
        Btx, leb, Bt0, Bt1, relW0, relW1);

    const int gemm_grid = (N_NODES + 63) / 64;  // 782

    mfma_in_kernel<<<gemm_grid, 256, 0, stream>>>(x, Btx, leb, label, in_proj_b, hb);

    // layer 0
    mfma_half_kernel<<<dim3(gemm_grid, 2), 256, 0, stream>>>(hb, Bt0, lin_self_b, hW, hsb);
    agg_ln_kernel<false, true><<<(N_NODES + 3) / 4, 256, 0, stream>>>(
        hW, relW0, hsb, offsets, csr_pk, ln_g, ln_b, h, hb);
    // layer 1
    mfma_half_kernel<<<dim3(gemm_grid, 2), 256, 0, stream>>>(hb, Bt1, lin_self_b + 128, hW, hsb);
    agg_ln_kernel<true, false><<<(N_NODES + 3) / 4, 256, 0, stream>>>(
        hW, relW1, hsb, offsets, csr_pk, ln_g + 128, ln_b + 128, h, hb);
}